// Round 1
// baseline (4718.739 us; speedup 1.0000x reference)
//
#include <hip/hip_runtime.h>
#include <hip/hip_bf16.h>

#define NN 20000
#define NE 320000
#define LL 16
#define TT 64
#define HH 128
#define VV 32000
#define CC 2
#define FF 8

__device__ inline unsigned short f32_to_bf16(float v) {
  unsigned int b = __float_as_uint(v);
  b += 0x7fffu + ((b >> 16) & 1u);
  return (unsigned short)(b >> 16);
}

// ---------------- small utility kernels ----------------
__global__ void fill_zero_k(float* __restrict__ p, int n) {
  int i = blockIdx.x * 256 + threadIdx.x;
  if (i < n) p[i] = 0.f;
}

__global__ void deg_k(const int* __restrict__ eidx, float* __restrict__ deg) {
  int e = blockIdx.x * 256 + threadIdx.x;
  if (e < NE) atomicAdd(&deg[eidx[NE + e]], 1.f);
}

__global__ void dinv_k(float* __restrict__ deg) {
  int i = blockIdx.x * 256 + threadIdx.x;
  if (i < NN) deg[i] = rsqrtf(deg[i] + 1.f);
}

// one wave (64 lanes) per edge; H=128 -> 2 elements/lane
__global__ void gcn_agg_k(const int* __restrict__ eidx, const float* __restrict__ xw,
                          const float* __restrict__ dinv, float* __restrict__ agg) {
  int e = blockIdx.x * 4 + (threadIdx.x >> 6);
  int lane = threadIdx.x & 63;
  if (e >= NE) return;
  int s = eidx[e], d = eidx[NE + e];
  float nrm = dinv[s] * dinv[d];
  atomicAdd(&agg[d * HH + lane],      xw[s * HH + lane] * nrm);
  atomicAdd(&agg[d * HH + 64 + lane], xw[s * HH + 64 + lane] * nrm);
}

__global__ void gcn_fin_k(const float* __restrict__ agg, const float* __restrict__ xw,
                          const float* __restrict__ dinv, const float* __restrict__ b,
                          float* __restrict__ out) {
  int i = blockIdx.x * 256 + threadIdx.x;
  if (i >= NN * HH) return;
  int n = i >> 7, h = i & 127;
  float di = dinv[n];
  out[i] = fmaxf(agg[i] + xw[i] * di * di + b[h], 0.f);
}

__global__ void gather_xt_k(const int* __restrict__ xtext, const float* __restrict__ embed,
                            float* __restrict__ xt, int t) {
  int i = blockIdx.x * 256 + threadIdx.x;
  if (i >= NN * TT) return;
  int n = i >> 6, k = i & 63;
  xt[i] = embed[(size_t)xtext[n * LL + t] * TT + k];
}

__global__ void gru_gates_k(const float* __restrict__ gi, const float* __restrict__ gh,
                            float* __restrict__ h, float* __restrict__ txt) {
  int i = blockIdx.x * 256 + threadIdx.x;
  if (i >= NN * HH) return;
  int n = i >> 7, j = i & 127;
  const float* gin = gi + (size_t)n * 384;
  const float* ghn = gh + (size_t)n * 384;
  float r  = 1.f / (1.f + __expf(-(gin[j] + ghn[j])));
  float z  = 1.f / (1.f + __expf(-(gin[128 + j] + ghn[128 + j])));
  float nn2 = tanhf(gin[256 + j] + r * ghn[256 + j]);
  float hv = h[i];
  float h2 = (1.f - z) * nn2 + z * hv;
  h[i] = h2;
  txt[i] += h2;
}

// ---------------- generic tiled f32 GEMM: C = A(MxK) * B(KxN) (+bias)(+relu) ----
// BM=BN=128, BK=16, 256 threads, 8x8 micro-tile per thread.
template<bool TRANSB, bool ADD_BIAS, bool RELU>
__global__ __launch_bounds__(256) void gemm_k(
    const float* __restrict__ A, const float* __restrict__ B,
    const float* __restrict__ bias, float* __restrict__ C,
    int M, int N, int K, int lda, int ldb, int ldc)
{
  __shared__ float As[16][132];
  __shared__ float Bs[16][132];
  int tid = threadIdx.x;
  int bm = blockIdx.y * 128, bn = blockIdx.x * 128;
  int tx = tid & 15, ty = tid >> 4;
  float acc[8][8];
#pragma unroll
  for (int i = 0; i < 8; ++i)
#pragma unroll
    for (int j = 0; j < 8; ++j) acc[i][j] = 0.f;

  for (int k0 = 0; k0 < K; k0 += 16) {
    // A tile: 128 rows x 16 k, float4 loads along k
#pragma unroll
    for (int l = 0; l < 2; ++l) {
      int s = tid + l * 256;          // 0..511
      int r = s >> 2, kq = s & 3;
      int gr = bm + r, gk = k0 + kq * 4;
      float4 v = make_float4(0.f, 0.f, 0.f, 0.f);
      if (gr < M && gk < K)
        v = *reinterpret_cast<const float4*>(&A[(size_t)gr * lda + gk]);
      As[kq * 4 + 0][r] = v.x; As[kq * 4 + 1][r] = v.y;
      As[kq * 4 + 2][r] = v.z; As[kq * 4 + 3][r] = v.w;
    }
    if (TRANSB) {
#pragma unroll
      for (int l = 0; l < 2; ++l) {
        int s = tid + l * 256;
        int c = s >> 2, kq = s & 3;
        int gc = bn + c, gk = k0 + kq * 4;
        float4 v = make_float4(0.f, 0.f, 0.f, 0.f);
        if (gc < N && gk < K)
          v = *reinterpret_cast<const float4*>(&B[(size_t)gc * ldb + gk]);
        Bs[kq * 4 + 0][c] = v.x; Bs[kq * 4 + 1][c] = v.y;
        Bs[kq * 4 + 2][c] = v.z; Bs[kq * 4 + 3][c] = v.w;
      }
    } else {
#pragma unroll
      for (int l = 0; l < 8; ++l) {
        int s = tid + l * 256;        // 0..2047
        int kk = s >> 7, c = s & 127;
        int gk = k0 + kk, gc = bn + c;
        Bs[kk][c] = (gk < K && gc < N) ? B[(size_t)gk * ldb + gc] : 0.f;
      }
    }
    __syncthreads();
#pragma unroll
    for (int kk = 0; kk < 16; ++kk) {
      float4 a0 = *reinterpret_cast<const float4*>(&As[kk][ty * 8]);
      float4 a1 = *reinterpret_cast<const float4*>(&As[kk][ty * 8 + 4]);
      float4 b0 = *reinterpret_cast<const float4*>(&Bs[kk][tx * 8]);
      float4 b1 = *reinterpret_cast<const float4*>(&Bs[kk][tx * 8 + 4]);
      float av[8] = {a0.x, a0.y, a0.z, a0.w, a1.x, a1.y, a1.z, a1.w};
      float bv[8] = {b0.x, b0.y, b0.z, b0.w, b1.x, b1.y, b1.z, b1.w};
#pragma unroll
      for (int i = 0; i < 8; ++i)
#pragma unroll
        for (int j = 0; j < 8; ++j)
          acc[i][j] += av[i] * bv[j];
    }
    __syncthreads();
  }
#pragma unroll
  for (int i = 0; i < 8; ++i) {
    int gr = bm + ty * 8 + i;
    if (gr >= M) continue;
#pragma unroll
    for (int j = 0; j < 8; ++j) {
      int gc = bn + tx * 8 + j;
      if (gc >= N) continue;
      float v = acc[i][j];
      if (ADD_BIAS) v += bias[gc];
      if (RELU) v = fmaxf(v, 0.f);
      C[(size_t)gr * ldc + gc] = v;
    }
  }
}

// ---------------- fused edge-head kernel ----------------
// Per block: 64 edges. Build e[64][384] = relu(A[src]+B[dst]) in LDS (bf16,
// transposed), then for each head: H = relu(e @ w1 + b1) kept in registers,
// logits = H @ w2 + b2 reduced via LDS atomics, log_softmax, store.
__global__ __launch_bounds__(256) void edge_head_k(
    const int* __restrict__ eidx,
    const float* __restrict__ Ap, const float* __restrict__ Bp,
    const float* __restrict__ At, const float* __restrict__ Bt,
    const float* __restrict__ Ai, const float* __restrict__ Bi,
    const float* __restrict__ rw1, const float* __restrict__ rb1,
    const float* __restrict__ rw2, const float* __restrict__ rb2,
    const float* __restrict__ cw1, const float* __restrict__ cb1,
    const float* __restrict__ cw2, const float* __restrict__ cb2,
    float* __restrict__ out)
{
  __shared__ unsigned short esT[384][68]; // bf16, transposed [k][edge], 52224 B
  __shared__ float ws[16][132];           // w1 k-chunk, 8448 B
  __shared__ float part_s[64][2];         // logits partials
  __shared__ int sd_s[2][64];

  int tid = threadIdx.x;
  int e0 = blockIdx.x * 64;
  if (tid < 64) {
    sd_s[0][tid] = eidx[e0 + tid];
    sd_s[1][tid] = eidx[NE + e0 + tid];
  }
  __syncthreads();

  for (int i = tid; i < 64 * 384; i += 256) {
    int el = i / 384, j = i - el * 384;
    int s = sd_s[0][el], d = sd_s[1][el];
    int jj = j & 127;
    float v;
    if (j < 128)      v = Ap[(size_t)s * HH + jj] + Bp[(size_t)d * HH + jj];
    else if (j < 256) v = At[(size_t)s * HH + jj] + Bt[(size_t)d * HH + jj];
    else              v = Ai[(size_t)s * HH + jj] + Bi[(size_t)d * HH + jj];
    v = fmaxf(v, 0.f);
    esT[j][el] = f32_to_bf16(v);
  }

  int te = tid & 15, tj = tid >> 4; // edges te*4..te*4+3, cols tj*8..tj*8+7

#pragma unroll 1
  for (int head = 0; head < 2; ++head) {
    const float* w1 = head ? cw1 : rw1;
    const float* b1 = head ? cb1 : rb1;
    const float* w2 = head ? cw2 : rw2;
    const float* b2 = head ? cb2 : rb2;

    float acc[4][8];
#pragma unroll
    for (int i = 0; i < 4; ++i)
#pragma unroll
      for (int j = 0; j < 8; ++j) acc[i][j] = 0.f;
    if (tid < 128) ((float*)part_s)[tid] = 0.f;

    for (int k0 = 0; k0 < 384; k0 += 16) {
      __syncthreads();
#pragma unroll
      for (int l = 0; l < 8; ++l) {
        int s = tid + l * 256;  // 16*128
        int kk = s >> 7, c = s & 127;
        ws[kk][c] = w1[(size_t)(k0 + kk) * HH + c];
      }
      __syncthreads();
#pragma unroll
      for (int k = 0; k < 16; ++k) {
        const uint2* row = reinterpret_cast<const uint2*>(&esT[k0 + k][0]);
        uint2 av = row[te];
        float a0 = __uint_as_float(av.x << 16);
        float a1 = __uint_as_float(av.x & 0xffff0000u);
        float a2 = __uint_as_float(av.y << 16);
        float a3 = __uint_as_float(av.y & 0xffff0000u);
        float4 b0 = *reinterpret_cast<const float4*>(&ws[k][tj * 8]);
        float4 b1v = *reinterpret_cast<const float4*>(&ws[k][tj * 8 + 4]);
        float aval[4] = {a0, a1, a2, a3};
        float bv[8] = {b0.x, b0.y, b0.z, b0.w, b1v.x, b1v.y, b1v.z, b1v.w};
#pragma unroll
        for (int i = 0; i < 4; ++i)
#pragma unroll
          for (int j = 0; j < 8; ++j)
            acc[i][j] += aval[i] * bv[j];
      }
    }

    // second layer partials: relu(acc + b1) @ w2
    float p0[4] = {0.f, 0.f, 0.f, 0.f}, p1[4] = {0.f, 0.f, 0.f, 0.f};
#pragma unroll
    for (int j = 0; j < 8; ++j) {
      int jg = tj * 8 + j;
      float w20 = w2[jg * 2 + 0], w21 = w2[jg * 2 + 1];
      float bb = b1[jg];
#pragma unroll
      for (int i = 0; i < 4; ++i) {
        float hv = fmaxf(acc[i][j] + bb, 0.f);
        p0[i] += hv * w20;
        p1[i] += hv * w21;
      }
    }
#pragma unroll
    for (int i = 0; i < 4; ++i) {
      atomicAdd(&part_s[te * 4 + i][0], p0[i]);
      atomicAdd(&part_s[te * 4 + i][1], p1[i]);
    }
    __syncthreads();
    if (tid < 64) {
      float l0 = part_s[tid][0] + b2[0];
      float l1 = part_s[tid][1] + b2[1];
      float m = fmaxf(l0, l1);
      float lse = m + __logf(__expf(l0 - m) + __expf(l1 - m));
      float* o = out + (size_t)head * (2 * NE) + (size_t)(e0 + tid) * 2;
      o[0] = l0 - lse;
      o[1] = l1 - lse;
    }
    __syncthreads();
  }
}

// ---------------- launch ----------------
extern "C" void kernel_launch(void* const* d_in, const int* in_sizes, int n_in,
                              void* d_out, int out_size, void* d_ws, size_t ws_size,
                              hipStream_t stream)
{
  const float* x       = (const float*)d_in[0];
  const int*   eidx    = (const int*)  d_in[1];
  const int*   xtext   = (const int*)  d_in[2];
  const float* imgf    = (const float*)d_in[3];
  const float* conv1_w = (const float*)d_in[4];
  const float* conv1_b = (const float*)d_in[5];
  const float* conv2_w = (const float*)d_in[6];
  const float* conv2_b = (const float*)d_in[7];
  const float* embed   = (const float*)d_in[8];
  const float* gwih    = (const float*)d_in[9];
  const float* gwhh    = (const float*)d_in[10];
  const float* gbih    = (const float*)d_in[11];
  const float* gbhh    = (const float*)d_in[12];
  const float* lpw     = (const float*)d_in[13];
  const float* lpb     = (const float*)d_in[14];
  const float* ltw     = (const float*)d_in[15];
  const float* ltb     = (const float*)d_in[16];
  const float* liw     = (const float*)d_in[17];
  const float* lib     = (const float*)d_in[18];
  const float* rw1     = (const float*)d_in[19];
  const float* rb1     = (const float*)d_in[20];
  const float* rw2     = (const float*)d_in[21];
  const float* rb2     = (const float*)d_in[22];
  const float* cw1     = (const float*)d_in[23];
  const float* cb1     = (const float*)d_in[24];
  const float* cw2     = (const float*)d_in[25];
  const float* cb2     = (const float*)d_in[26];
  float* out = (float*)d_out;

  // workspace layout (floats); total ~29.46M floats (~118 MB)
  float* wsf    = (float*)d_ws;
  float* xw     = wsf;                          // [N,128]
  float* agg    = xw     + (size_t)NN * HH;     // [N,128]
  float* hbuf   = agg    + (size_t)NN * HH;     // [N,128] h1 then pos
  float* txt    = hbuf   + (size_t)NN * HH;     // [N,128]
  float* hstate = txt    + (size_t)NN * HH;     // [N,128]
  float* xt     = hstate + (size_t)NN * HH;     // [N,64]
  float* gi     = xt     + (size_t)NN * TT;     // [N,384]
  float* gh     = gi     + (size_t)NN * 384;    // [N,384]
  float* dinv   = gh     + (size_t)NN * 384;    // [N]
  // node tables overlay gi/gh (GRU finished before these are built)
  float* Ap = gi;
  float* Bp = gi + (size_t)NN * HH;
  float* At = gi + (size_t)2 * NN * HH;
  float* Bt = gh;
  float* Ai = gh + (size_t)NN * HH;
  float* Bi = gh + (size_t)2 * NN * HH;

  dim3 b256(256);
  auto cdiv = [](int a, int b) { return (a + b - 1) / b; };
  const int MB = cdiv(NN, 128); // 157

  // degree -> dinv
  fill_zero_k<<<cdiv(NN, 256), b256, 0, stream>>>(dinv, NN);
  deg_k<<<cdiv(NE, 256), b256, 0, stream>>>(eidx, dinv);
  dinv_k<<<cdiv(NN, 256), b256, 0, stream>>>(dinv);

  // GCN layer 1
  gemm_k<false, false, false><<<dim3(1, MB), b256, 0, stream>>>(x, conv1_w, nullptr, xw, NN, 128, 8, 8, 128, 128);
  fill_zero_k<<<cdiv(NN * HH, 256), b256, 0, stream>>>(agg, NN * HH);
  gcn_agg_k<<<NE / 4, b256, 0, stream>>>(eidx, xw, dinv, agg);
  gcn_fin_k<<<cdiv(NN * HH, 256), b256, 0, stream>>>(agg, xw, dinv, conv1_b, hbuf);
  // GCN layer 2
  gemm_k<false, false, false><<<dim3(1, MB), b256, 0, stream>>>(hbuf, conv2_w, nullptr, xw, NN, 128, 128, 128, 128, 128);
  fill_zero_k<<<cdiv(NN * HH, 256), b256, 0, stream>>>(agg, NN * HH);
  gcn_agg_k<<<NE / 4, b256, 0, stream>>>(eidx, xw, dinv, agg);
  gcn_fin_k<<<cdiv(NN * HH, 256), b256, 0, stream>>>(agg, xw, dinv, conv2_b, hbuf); // pos

  // GRU over L=16 steps
  fill_zero_k<<<cdiv(NN * HH, 256), b256, 0, stream>>>(txt, NN * HH);
  fill_zero_k<<<cdiv(NN * HH, 256), b256, 0, stream>>>(hstate, NN * HH);
  for (int t = 0; t < LL; ++t) {
    gather_xt_k<<<cdiv(NN * TT, 256), b256, 0, stream>>>(xtext, embed, xt, t);
    gemm_k<true, true, false><<<dim3(3, MB), b256, 0, stream>>>(xt, gwih, gbih, gi, NN, 384, 64, 64, 64, 384);
    gemm_k<true, true, false><<<dim3(3, MB), b256, 0, stream>>>(hstate, gwhh, gbhh, gh, NN, 384, 128, 128, 128, 384);
    gru_gates_k<<<cdiv(NN * HH, 256), b256, 0, stream>>>(gi, gh, hstate, txt);
  }

  // node-level tables for edge MLPs: cat(f[s],f[d])@W = (f@Wtop)[s] + (f@Wbot)[d]
  gemm_k<false, false, false><<<dim3(1, MB), b256, 0, stream>>>(hbuf, lpw,            nullptr, Ap, NN, 128, 128, 128, 128, 128);
  gemm_k<false, true,  false><<<dim3(1, MB), b256, 0, stream>>>(hbuf, lpw + 128*128,  lpb,     Bp, NN, 128, 128, 128, 128, 128);
  gemm_k<false, false, false><<<dim3(1, MB), b256, 0, stream>>>(txt,  ltw,            nullptr, At, NN, 128, 128, 128, 128, 128);
  gemm_k<false, true,  false><<<dim3(1, MB), b256, 0, stream>>>(txt,  ltw + 128*128,  ltb,     Bt, NN, 128, 128, 128, 128, 128);
  gemm_k<false, false, false><<<dim3(1, MB), b256, 0, stream>>>(imgf, liw,            nullptr, Ai, NN, 128, 256, 256, 128, 128);
  gemm_k<false, true,  false><<<dim3(1, MB), b256, 0, stream>>>(imgf, liw + 256*128,  lib,     Bi, NN, 128, 256, 256, 128, 128);

  // fused edge heads + log_softmax
  edge_head_k<<<NE / 64, b256, 0, stream>>>(eidx, Ap, Bp, At, Bt, Ai, Bi,
                                            rw1, rb1, rw2, rb2, cw1, cb1, cw2, cb2, out);
}

// Round 2
// 2403.697 us; speedup vs baseline: 1.9631x; 1.9631x over previous
//
#include <hip/hip_runtime.h>
#include <hip/hip_bf16.h>

#define NN 20000
#define NE 320000
#define LL 16
#define TT 64
#define HH 128

typedef __attribute__((ext_vector_type(8))) short short8v;
typedef __attribute__((ext_vector_type(4))) float f32x4;
#define MFMA_BF16(a,b,c) __builtin_amdgcn_mfma_f32_16x16x32_bf16(a,b,c,0,0,0)

__device__ inline unsigned short f32_to_bf16(float v) {
  unsigned int b = __float_as_uint(v);
  b += 0x7fffu + ((b >> 16) & 1u);
  return (unsigned short)(b >> 16);
}
__device__ inline float bf16_to_f32(unsigned short u) {
  return __uint_as_float(((unsigned int)u) << 16);
}
__device__ inline float sigmoidf_(float x) { return 1.f / (1.f + __expf(-x)); }

// ---------------- small utility kernels ----------------
__global__ void fill_zero_k(float* __restrict__ p, int n) {
  int i = blockIdx.x * 256 + threadIdx.x;
  if (i < n) p[i] = 0.f;
}

__global__ void deg_k(const int* __restrict__ eidx, float* __restrict__ deg) {
  int e = blockIdx.x * 256 + threadIdx.x;
  if (e < NE) atomicAdd(&deg[eidx[NE + e]], 1.f);
}

__global__ void dinv_k(float* __restrict__ deg) {
  int i = blockIdx.x * 256 + threadIdx.x;
  if (i < NN) deg[i] = rsqrtf(deg[i] + 1.f);
}

__global__ void gcn_agg_k(const int* __restrict__ eidx, const float* __restrict__ xw,
                          const float* __restrict__ dinv, float* __restrict__ agg) {
  int e = blockIdx.x * 4 + (threadIdx.x >> 6);
  int lane = threadIdx.x & 63;
  if (e >= NE) return;
  int s = eidx[e], d = eidx[NE + e];
  float nrm = dinv[s] * dinv[d];
  atomicAdd(&agg[d * HH + lane],      xw[s * HH + lane] * nrm);
  atomicAdd(&agg[d * HH + 64 + lane], xw[s * HH + 64 + lane] * nrm);
}

__global__ void gcn_fin_k(const float* __restrict__ agg, const float* __restrict__ xw,
                          const float* __restrict__ dinv, const float* __restrict__ b,
                          float* __restrict__ out) {
  int i = blockIdx.x * 256 + threadIdx.x;
  if (i >= NN * HH) return;
  int n = i >> 7, h = i & 127;
  float di = dinv[n];
  out[i] = fmaxf(agg[i] + xw[i] * di * di + b[h], 0.f);
}

__global__ void cvt_bf16_k(const float* __restrict__ in, unsigned short* __restrict__ out, int n) {
  int i = blockIdx.x * 256 + threadIdx.x;
  if (i < n) out[i] = f32_to_bf16(in[i]);
}

// in[R][C] -> out[C][R] bf16
__global__ void transpose_bf16_k(const float* __restrict__ in, unsigned short* __restrict__ out,
                                 int R, int C) {
  int i = blockIdx.x * 256 + threadIdx.x;
  if (i >= R * C) return;
  int c = i / R, r = i - c * R;
  out[i] = f32_to_bf16(in[r * C + c]);
}

__global__ void gru_bias_k(const float* __restrict__ bih, const float* __restrict__ bhh,
                           float* __restrict__ brz, float* __restrict__ binv, float* __restrict__ bhnv) {
  int i = blockIdx.x * 256 + threadIdx.x;
  if (i < 256) brz[i] = bih[i] + bhh[i];
  else if (i < 384) binv[i - 256] = bih[i];
  else if (i < 512) bhnv[i - 384] = bhh[i - 128];
}

// ---------------- generic tiled f32 GEMM (unchanged, used for GCN + tables) ----
template<bool TRANSB, bool ADD_BIAS, bool RELU>
__global__ __launch_bounds__(256) void gemm_k(
    const float* __restrict__ A, const float* __restrict__ B,
    const float* __restrict__ bias, float* __restrict__ C,
    int M, int N, int K, int lda, int ldb, int ldc)
{
  __shared__ float As[16][132];
  __shared__ float Bs[16][132];
  int tid = threadIdx.x;
  int bm = blockIdx.y * 128, bn = blockIdx.x * 128;
  int tx = tid & 15, ty = tid >> 4;
  float acc[8][8];
#pragma unroll
  for (int i = 0; i < 8; ++i)
#pragma unroll
    for (int j = 0; j < 8; ++j) acc[i][j] = 0.f;

  for (int k0 = 0; k0 < K; k0 += 16) {
#pragma unroll
    for (int l = 0; l < 2; ++l) {
      int s = tid + l * 256;
      int r = s >> 2, kq = s & 3;
      int gr = bm + r, gk = k0 + kq * 4;
      float4 v = make_float4(0.f, 0.f, 0.f, 0.f);
      if (gr < M && gk < K)
        v = *reinterpret_cast<const float4*>(&A[(size_t)gr * lda + gk]);
      As[kq * 4 + 0][r] = v.x; As[kq * 4 + 1][r] = v.y;
      As[kq * 4 + 2][r] = v.z; As[kq * 4 + 3][r] = v.w;
    }
    if (TRANSB) {
#pragma unroll
      for (int l = 0; l < 2; ++l) {
        int s = tid + l * 256;
        int c = s >> 2, kq = s & 3;
        int gc = bn + c, gk = k0 + kq * 4;
        float4 v = make_float4(0.f, 0.f, 0.f, 0.f);
        if (gc < N && gk < K)
          v = *reinterpret_cast<const float4*>(&B[(size_t)gc * ldb + gk]);
        Bs[kq * 4 + 0][c] = v.x; Bs[kq * 4 + 1][c] = v.y;
        Bs[kq * 4 + 2][c] = v.z; Bs[kq * 4 + 3][c] = v.w;
      }
    } else {
#pragma unroll
      for (int l = 0; l < 8; ++l) {
        int s = tid + l * 256;
        int kk = s >> 7, c = s & 127;
        int gk = k0 + kk, gc = bn + c;
        Bs[kk][c] = (gk < K && gc < N) ? B[(size_t)gk * ldb + gc] : 0.f;
      }
    }
    __syncthreads();
#pragma unroll
    for (int kk = 0; kk < 16; ++kk) {
      float4 a0 = *reinterpret_cast<const float4*>(&As[kk][ty * 8]);
      float4 a1 = *reinterpret_cast<const float4*>(&As[kk][ty * 8 + 4]);
      float4 b0 = *reinterpret_cast<const float4*>(&Bs[kk][tx * 8]);
      float4 b1 = *reinterpret_cast<const float4*>(&Bs[kk][tx * 8 + 4]);
      float av[8] = {a0.x, a0.y, a0.z, a0.w, a1.x, a1.y, a1.z, a1.w};
      float bv[8] = {b0.x, b0.y, b0.z, b0.w, b1.x, b1.y, b1.z, b1.w};
#pragma unroll
      for (int i = 0; i < 8; ++i)
#pragma unroll
        for (int j = 0; j < 8; ++j)
          acc[i][j] += av[i] * bv[j];
    }
    __syncthreads();
  }
#pragma unroll
  for (int i = 0; i < 8; ++i) {
    int gr = bm + ty * 8 + i;
    if (gr >= M) continue;
#pragma unroll
    for (int j = 0; j < 8; ++j) {
      int gc = bn + tx * 8 + j;
      if (gc >= N) continue;
      float v = acc[i][j];
      if (ADD_BIAS) v += bias[gc];
      if (RELU) v = fmaxf(v, 0.f);
      C[(size_t)gr * ldc + gc] = v;
    }
  }
}

// ---------------- fused persistent GRU (64 nodes/block, all 16 steps) --------
__global__ __launch_bounds__(256) void gru_fused_k(
    const int* __restrict__ xtext, const float* __restrict__ embed,
    const unsigned short* __restrict__ wihB, const unsigned short* __restrict__ whhB,
    const float* __restrict__ brz, const float* __restrict__ binv, const float* __restrict__ bhnv,
    float* __restrict__ txt)
{
  __shared__ unsigned char hs[64 * 256];  // h tile bf16 [64][128], XOR-swizzled
  __shared__ unsigned char xs[64 * 128];  // xt tile bf16 [64][64], XOR-swizzled
  const int tid = threadIdx.x;
  const int n0 = blockIdx.x * 64;
  const int wid = tid >> 6, lane = tid & 63;
  const int l16 = lane & 15, lk = lane >> 4;
  const int wrow = wid * 16;

  for (int i = tid; i < 64 * 256 / 4; i += 256) ((unsigned int*)hs)[i] = 0u;

  float txtacc[4][8];
#pragma unroll
  for (int r = 0; r < 4; ++r)
#pragma unroll
    for (int f = 0; f < 8; ++f) txtacc[r][f] = 0.f;

  const int arow = wrow + l16;
  const int asw = (arow & 7) << 4;

  for (int t = 0; t < LL; ++t) {
    __syncthreads();
    {
      const int k4 = tid & 15, r0 = tid >> 4;
#pragma unroll
      for (int rep = 0; rep < 4; ++rep) {
        int row = r0 + rep * 16;
        int n = n0 + row; if (n >= NN) n = NN - 1;
        int tok = xtext[n * LL + t];
        float4 v = *reinterpret_cast<const float4*>(&embed[(size_t)tok * TT + k4 * 4]);
        ushort4 w;
        w.x = f32_to_bf16(v.x); w.y = f32_to_bf16(v.y);
        w.z = f32_to_bf16(v.z); w.w = f32_to_bf16(v.w);
        *reinterpret_cast<ushort4*>(&xs[row * 128 + ((k4 * 8) ^ ((row & 7) << 4))]) = w;
      }
    }
    __syncthreads();

    short8v ax[2], ah[4];
#pragma unroll
    for (int ks = 0; ks < 2; ++ks)
      ax[ks] = *reinterpret_cast<const short8v*>(&xs[arow * 128 + ((ks * 64 + lk * 16) ^ asw)]);
#pragma unroll
    for (int ks = 0; ks < 4; ++ks)
      ah[ks] = *reinterpret_cast<const short8v*>(&hs[arow * 256 + ((ks * 64 + lk * 16) ^ asw)]);

    f32x4 arz[16], ain[8], ahn[8];
#pragma unroll
    for (int f = 0; f < 16; ++f) arz[f] = f32x4{0.f, 0.f, 0.f, 0.f};
#pragma unroll
    for (int f = 0; f < 8; ++f) { ain[f] = f32x4{0.f, 0.f, 0.f, 0.f}; ahn[f] = f32x4{0.f, 0.f, 0.f, 0.f}; }

#pragma unroll
    for (int f = 0; f < 16; ++f) {
      int col = f * 16 + l16;
#pragma unroll
      for (int ks = 0; ks < 2; ++ks) {
        short8v b = *reinterpret_cast<const short8v*>(&wihB[col * 64 + ks * 32 + lk * 8]);
        arz[f] = MFMA_BF16(ax[ks], b, arz[f]);
      }
#pragma unroll
      for (int ks = 0; ks < 4; ++ks) {
        short8v b = *reinterpret_cast<const short8v*>(&whhB[col * 128 + ks * 32 + lk * 8]);
        arz[f] = MFMA_BF16(ah[ks], b, arz[f]);
      }
    }
#pragma unroll
    for (int f = 0; f < 8; ++f) {
      int col = 256 + f * 16 + l16;
#pragma unroll
      for (int ks = 0; ks < 2; ++ks) {
        short8v b = *reinterpret_cast<const short8v*>(&wihB[col * 64 + ks * 32 + lk * 8]);
        ain[f] = MFMA_BF16(ax[ks], b, ain[f]);
      }
#pragma unroll
      for (int ks = 0; ks < 4; ++ks) {
        short8v b = *reinterpret_cast<const short8v*>(&whhB[col * 128 + ks * 32 + lk * 8]);
        ahn[f] = MFMA_BF16(ah[ks], b, ahn[f]);
      }
    }

    // gates: fully lane-local thanks to C-layout (col = lane&15 + 16*nf)
#pragma unroll
    for (int f = 0; f < 8; ++f) {
      int j = f * 16 + l16;
      float brj = brz[j], bzj = brz[128 + j], bij = binv[j], bhj = bhnv[j];
#pragma unroll
      for (int reg = 0; reg < 4; ++reg) {
        int row = wrow + lk * 4 + reg;
        int byte = row * 256 + ((j * 2) ^ ((row & 7) << 4));
        float hold = bf16_to_f32(*reinterpret_cast<unsigned short*>(&hs[byte]));
        float rg = sigmoidf_(arz[f][reg] + brj);
        float zg = sigmoidf_(arz[f + 8][reg] + bzj);
        float ng = tanhf(ain[f][reg] + bij + rg * (ahn[f][reg] + bhj));
        float h2 = (1.f - zg) * ng + zg * hold;
        txtacc[reg][f] += h2;
        *reinterpret_cast<unsigned short*>(&hs[byte]) = f32_to_bf16(h2);
      }
    }
  }

#pragma unroll
  for (int f = 0; f < 8; ++f) {
#pragma unroll
    for (int reg = 0; reg < 4; ++reg) {
      int row = wrow + lk * 4 + reg;
      int n = n0 + row;
      if (n < NN) txt[(size_t)n * HH + f * 16 + l16] = txtacc[reg][f];
    }
  }
}

// ---------------- fused edge heads via MFMA ----------------
// Block: 128 edges. A-tile (e) staged per 64-K-chunk in LDS bf16 (XOR-swizzled),
// shared by both heads. Wave = 32 rows x 128 cols. Epilogue: layer2 + log_softmax
// via shfl reduction over the 16-lane col groups.
__global__ __launch_bounds__(256) void edge_mfma_k(
    const int* __restrict__ eidx,
    const float* __restrict__ Ap, const float* __restrict__ Bp,
    const float* __restrict__ At, const float* __restrict__ Bt,
    const float* __restrict__ Ai, const float* __restrict__ Bi,
    const unsigned short* __restrict__ rw1T, const float* __restrict__ rb1,
    const float* __restrict__ rw2, const float* __restrict__ rb2,
    const unsigned short* __restrict__ cw1T, const float* __restrict__ cb1,
    const float* __restrict__ cw2, const float* __restrict__ cb2,
    float* __restrict__ out)
{
  __shared__ unsigned char es[128 * 128]; // [128 edges][64 k] bf16, swizzled (16KB)
  __shared__ int sd[2][128];
  const int tid = threadIdx.x;
  const int e0 = blockIdx.x * 128;
  const int wid = tid >> 6, lane = tid & 63;
  const int l16 = lane & 15, lk = lane >> 4;
  const int wr = wid * 32;

  if (tid < 128) { sd[0][tid] = eidx[e0 + tid]; sd[1][tid] = eidx[NE + e0 + tid]; }

  f32x4 acc[2][2][8];
#pragma unroll
  for (int h = 0; h < 2; ++h)
#pragma unroll
    for (int mf = 0; mf < 2; ++mf)
#pragma unroll
      for (int nf = 0; nf < 8; ++nf) acc[h][mf][nf] = f32x4{0.f, 0.f, 0.f, 0.f};

#pragma unroll
  for (int c = 0; c < 6; ++c) {
    const float* Asrc = (c < 2 ? Ap : c < 4 ? At : Ai) + (c & 1) * 64;
    const float* Bsrc = (c < 2 ? Bp : c < 4 ? Bt : Bi) + (c & 1) * 64;
    __syncthreads();
    {
      int k4 = tid & 15, el0 = tid >> 4;
#pragma unroll
      for (int rep = 0; rep < 8; ++rep) {
        int el = el0 + rep * 16;
        int s = sd[0][el], d = sd[1][el];
        float4 va = *reinterpret_cast<const float4*>(&Asrc[(size_t)s * HH + k4 * 4]);
        float4 vb = *reinterpret_cast<const float4*>(&Bsrc[(size_t)d * HH + k4 * 4]);
        ushort4 w;
        w.x = f32_to_bf16(fmaxf(va.x + vb.x, 0.f));
        w.y = f32_to_bf16(fmaxf(va.y + vb.y, 0.f));
        w.z = f32_to_bf16(fmaxf(va.z + vb.z, 0.f));
        w.w = f32_to_bf16(fmaxf(va.w + vb.w, 0.f));
        *reinterpret_cast<ushort4*>(&es[el * 128 + ((k4 * 8) ^ ((el & 7) << 4))]) = w;
      }
    }
    __syncthreads();
#pragma unroll
    for (int ks = 0; ks < 2; ++ks) {
      short8v a[2];
#pragma unroll
      for (int mf = 0; mf < 2; ++mf) {
        int row = wr + mf * 16 + l16;
        a[mf] = *reinterpret_cast<const short8v*>(&es[row * 128 + ((ks * 64 + lk * 16) ^ ((row & 7) << 4))]);
      }
      int kglob = c * 64 + ks * 32 + lk * 8;
#pragma unroll
      for (int h = 0; h < 2; ++h) {
        const unsigned short* w1T = h ? cw1T : rw1T;
#pragma unroll
        for (int nf = 0; nf < 8; ++nf) {
          int col = nf * 16 + l16;
          short8v b = *reinterpret_cast<const short8v*>(&w1T[(size_t)col * 384 + kglob]);
          acc[h][0][nf] = MFMA_BF16(a[0], b, acc[h][0][nf]);
          acc[h][1][nf] = MFMA_BF16(a[1], b, acc[h][1][nf]);
        }
      }
    }
  }

  // epilogue: H = relu(acc + b1); logits = H @ w2 + b2; log_softmax; store
#pragma unroll
  for (int h = 0; h < 2; ++h) {
    const float* b1 = h ? cb1 : rb1;
    const float* w2 = h ? cw2 : rw2;
    const float* b2 = h ? cb2 : rb2;
#pragma unroll
    for (int mf = 0; mf < 2; ++mf) {
#pragma unroll
      for (int reg = 0; reg < 4; ++reg) {
        float p0 = 0.f, p1 = 0.f;
#pragma unroll
        for (int nf = 0; nf < 8; ++nf) {
          int col = nf * 16 + l16;
          float hv = fmaxf(acc[h][mf][nf][reg] + b1[col], 0.f);
          p0 += hv * w2[col * 2];
          p1 += hv * w2[col * 2 + 1];
        }
#pragma unroll
        for (int m = 1; m < 16; m <<= 1) {
          p0 += __shfl_xor(p0, m);
          p1 += __shfl_xor(p1, m);
        }
        if (l16 == 0) {
          float l0 = p0 + b2[0], l1 = p1 + b2[1];
          float mx = fmaxf(l0, l1);
          float lse = mx + __logf(__expf(l0 - mx) + __expf(l1 - mx));
          int edge = e0 + wr + mf * 16 + lk * 4 + reg;
          float2 o2 = make_float2(l0 - lse, l1 - lse);
          *reinterpret_cast<float2*>(&out[(size_t)h * 2 * NE + (size_t)edge * 2]) = o2;
        }
      }
    }
  }
}

// ---------------- launch ----------------
extern "C" void kernel_launch(void* const* d_in, const int* in_sizes, int n_in,
                              void* d_out, int out_size, void* d_ws, size_t ws_size,
                              hipStream_t stream)
{
  const float* x       = (const float*)d_in[0];
  const int*   eidx    = (const int*)  d_in[1];
  const int*   xtext   = (const int*)  d_in[2];
  const float* imgf    = (const float*)d_in[3];
  const float* conv1_w = (const float*)d_in[4];
  const float* conv1_b = (const float*)d_in[5];
  const float* conv2_w = (const float*)d_in[6];
  const float* conv2_b = (const float*)d_in[7];
  const float* embed   = (const float*)d_in[8];
  const float* gwih    = (const float*)d_in[9];
  const float* gwhh    = (const float*)d_in[10];
  const float* gbih    = (const float*)d_in[11];
  const float* gbhh    = (const float*)d_in[12];
  const float* lpw     = (const float*)d_in[13];
  const float* lpb     = (const float*)d_in[14];
  const float* ltw     = (const float*)d_in[15];
  const float* ltb     = (const float*)d_in[16];
  const float* liw     = (const float*)d_in[17];
  const float* lib     = (const float*)d_in[18];
  const float* rw1     = (const float*)d_in[19];
  const float* rb1     = (const float*)d_in[20];
  const float* rw2     = (const float*)d_in[21];
  const float* rb2     = (const float*)d_in[22];
  const float* cw1     = (const float*)d_in[23];
  const float* cb1     = (const float*)d_in[24];
  const float* cw2     = (const float*)d_in[25];
  const float* cb2     = (const float*)d_in[26];
  float* out = (float*)d_out;

  float* wsf = (float*)d_ws;
  size_t o = 0;
  auto alloc = [&](size_t n) { float* p = wsf + o; o += n; return p; };
  float* xw   = alloc((size_t)NN * HH);
  float* agg  = alloc((size_t)NN * HH);
  float* pos  = alloc((size_t)NN * HH);   // h1, then pos
  float* txt  = alloc((size_t)NN * HH);
  float* dinv = alloc(NN);
  float* Ap = alloc((size_t)NN * HH);
  float* Bp = alloc((size_t)NN * HH);
  float* At = alloc((size_t)NN * HH);
  float* Bt = alloc((size_t)NN * HH);
  float* Ai = alloc((size_t)NN * HH);
  float* Bi = alloc((size_t)NN * HH);
  unsigned short* wihB = (unsigned short*)alloc(384 * 64 / 2);
  unsigned short* whhB = (unsigned short*)alloc(384 * 128 / 2);
  unsigned short* rw1T = (unsigned short*)alloc(384 * 128 / 2);
  unsigned short* cw1T = (unsigned short*)alloc(384 * 128 / 2);
  float* brz  = alloc(256);
  float* binv = alloc(128);
  float* bhnv = alloc(128);

  dim3 b256(256);
  auto cdiv = [](int a, int b) { return (a + b - 1) / b; };
  const int MB = cdiv(NN, 128); // 157

  // weight conversions (independent of everything else)
  cvt_bf16_k<<<cdiv(384 * 64, 256), b256, 0, stream>>>(gwih, wihB, 384 * 64);
  cvt_bf16_k<<<cdiv(384 * 128, 256), b256, 0, stream>>>(gwhh, whhB, 384 * 128);
  transpose_bf16_k<<<cdiv(384 * 128, 256), b256, 0, stream>>>(rw1, rw1T, 384, 128);
  transpose_bf16_k<<<cdiv(384 * 128, 256), b256, 0, stream>>>(cw1, cw1T, 384, 128);
  gru_bias_k<<<2, b256, 0, stream>>>(gbih, gbhh, brz, binv, bhnv);

  // degree -> dinv
  fill_zero_k<<<cdiv(NN, 256), b256, 0, stream>>>(dinv, NN);
  deg_k<<<cdiv(NE, 256), b256, 0, stream>>>(eidx, dinv);
  dinv_k<<<cdiv(NN, 256), b256, 0, stream>>>(dinv);

  // GCN layer 1
  gemm_k<false, false, false><<<dim3(1, MB), b256, 0, stream>>>(x, conv1_w, nullptr, xw, NN, 128, 8, 8, 128, 128);
  fill_zero_k<<<cdiv(NN * HH, 256), b256, 0, stream>>>(agg, NN * HH);
  gcn_agg_k<<<NE / 4, b256, 0, stream>>>(eidx, xw, dinv, agg);
  gcn_fin_k<<<cdiv(NN * HH, 256), b256, 0, stream>>>(agg, xw, dinv, conv1_b, pos); // = h1
  // GCN layer 2
  gemm_k<false, false, false><<<dim3(1, MB), b256, 0, stream>>>(pos, conv2_w, nullptr, xw, NN, 128, 128, 128, 128, 128);
  fill_zero_k<<<cdiv(NN * HH, 256), b256, 0, stream>>>(agg, NN * HH);
  gcn_agg_k<<<NE / 4, b256, 0, stream>>>(eidx, xw, dinv, agg);
  gcn_fin_k<<<cdiv(NN * HH, 256), b256, 0, stream>>>(agg, xw, dinv, conv2_b, pos); // = pos

  // fused GRU (txt)
  gru_fused_k<<<cdiv(NN, 64), b256, 0, stream>>>(xtext, embed, wihB, whhB, brz, binv, bhnv, txt);

  // node-level tables: cat(f[s],f[d])@W = (f@Wtop)[s] + (f@Wbot)[d]
  gemm_k<false, false, false><<<dim3(1, MB), b256, 0, stream>>>(pos,  lpw,           nullptr, Ap, NN, 128, 128, 128, 128, 128);
  gemm_k<false, true,  false><<<dim3(1, MB), b256, 0, stream>>>(pos,  lpw + 128*128, lpb,     Bp, NN, 128, 128, 128, 128, 128);
  gemm_k<false, false, false><<<dim3(1, MB), b256, 0, stream>>>(txt,  ltw,           nullptr, At, NN, 128, 128, 128, 128, 128);
  gemm_k<false, true,  false><<<dim3(1, MB), b256, 0, stream>>>(txt,  ltw + 128*128, ltb,     Bt, NN, 128, 128, 128, 128, 128);
  gemm_k<false, false, false><<<dim3(1, MB), b256, 0, stream>>>(imgf, liw,           nullptr, Ai, NN, 128, 256, 256, 128, 128);
  gemm_k<false, true,  false><<<dim3(1, MB), b256, 0, stream>>>(imgf, liw + 256*128, lib,     Bi, NN, 128, 256, 256, 128, 128);

  // fused edge heads (MFMA) + log_softmax
  edge_mfma_k<<<NE / 128, b256, 0, stream>>>(eidx, Ap, Bp, At, Bt, Ai, Bi,
                                             rw1T, rb1, rw2, rb2, cw1T, cb1, cw2, cb2, out);
}

// Round 3
// 1515.769 us; speedup vs baseline: 3.1131x; 1.5858x over previous
//
#include <hip/hip_runtime.h>
#include <hip/hip_bf16.h>

#define NN 20000
#define NE 320000
#define LL 16
#define TT 64
#define HH 128

typedef __attribute__((ext_vector_type(8))) short short8v;
typedef __attribute__((ext_vector_type(4))) float f32x4;
#define MFMA_BF16(a,b,c) __builtin_amdgcn_mfma_f32_16x16x32_bf16(a,b,c,0,0,0)

__device__ inline unsigned short f32_to_bf16(float v) {
  unsigned int b = __float_as_uint(v);
  b += 0x7fffu + ((b >> 16) & 1u);
  return (unsigned short)(b >> 16);
}
__device__ inline float bf16_to_f32(unsigned short u) {
  return __uint_as_float(((unsigned int)u) << 16);
}
__device__ inline float fast_sigmoid(float x) {
  return __builtin_amdgcn_rcpf(1.f + __expf(-x));
}
__device__ inline float fast_tanh(float x) {
  float e = __expf(2.f * x);
  return 1.f - 2.f * __builtin_amdgcn_rcpf(e + 1.f);
}

// ---------------- small utility kernels ----------------
__global__ void fill_zero_k(float* __restrict__ p, int n) {
  int i = blockIdx.x * 256 + threadIdx.x;
  if (i < n) p[i] = 0.f;
}

__global__ void deg_k(const int* __restrict__ eidx, float* __restrict__ deg) {
  int e = blockIdx.x * 256 + threadIdx.x;
  if (e < NE) atomicAdd(&deg[eidx[NE + e]], 1.f);
}

__global__ void dinv_k(float* __restrict__ deg) {
  int i = blockIdx.x * 256 + threadIdx.x;
  if (i < NN) deg[i] = rsqrtf(deg[i] + 1.f);
}

__global__ void gcn_agg_k(const int* __restrict__ eidx, const float* __restrict__ xw,
                          const float* __restrict__ dinv, float* __restrict__ agg) {
  int e = blockIdx.x * 4 + (threadIdx.x >> 6);
  int lane = threadIdx.x & 63;
  if (e >= NE) return;
  int s = eidx[e], d = eidx[NE + e];
  float nrm = dinv[s] * dinv[d];
  atomicAdd(&agg[d * HH + lane],      xw[s * HH + lane] * nrm);
  atomicAdd(&agg[d * HH + 64 + lane], xw[s * HH + 64 + lane] * nrm);
}

__global__ void gcn_fin_k(const float* __restrict__ agg, const float* __restrict__ xw,
                          const float* __restrict__ dinv, const float* __restrict__ b,
                          float* __restrict__ out) {
  int i = blockIdx.x * 256 + threadIdx.x;
  if (i >= NN * HH) return;
  int n = i >> 7, h = i & 127;
  float di = dinv[n];
  out[i] = fmaxf(agg[i] + xw[i] * di * di + b[h], 0.f);
}

__global__ void cvt_bf16_k(const float* __restrict__ in, unsigned short* __restrict__ out, int n) {
  int i = blockIdx.x * 256 + threadIdx.x;
  if (i < n) out[i] = f32_to_bf16(in[i]);
}

// in[R][C] -> out[C][R] bf16
__global__ void transpose_bf16_k(const float* __restrict__ in, unsigned short* __restrict__ out,
                                 int R, int C) {
  int i = blockIdx.x * 256 + threadIdx.x;
  if (i >= R * C) return;
  int c = i / R, r = i - c * R;
  out[i] = f32_to_bf16(in[r * C + c]);
}

__global__ void gru_bias_k(const float* __restrict__ bih, const float* __restrict__ bhh,
                           float* __restrict__ brz, float* __restrict__ binv, float* __restrict__ bhnv) {
  int i = blockIdx.x * 256 + threadIdx.x;
  if (i < 256) brz[i] = bih[i] + bhh[i];
  else if (i < 384) binv[i - 256] = bih[i];
  else if (i < 512) bhnv[i - 384] = bhh[i - 128];
}

// ---------------- generic tiled f32 GEMM (GCN + node tables) ----
template<bool TRANSB, bool ADD_BIAS, bool RELU>
__global__ __launch_bounds__(256) void gemm_k(
    const float* __restrict__ A, const float* __restrict__ B,
    const float* __restrict__ bias, float* __restrict__ C,
    int M, int N, int K, int lda, int ldb, int ldc)
{
  __shared__ float As[16][132];
  __shared__ float Bs[16][132];
  int tid = threadIdx.x;
  int bm = blockIdx.y * 128, bn = blockIdx.x * 128;
  int tx = tid & 15, ty = tid >> 4;
  float acc[8][8];
#pragma unroll
  for (int i = 0; i < 8; ++i)
#pragma unroll
    for (int j = 0; j < 8; ++j) acc[i][j] = 0.f;

  for (int k0 = 0; k0 < K; k0 += 16) {
#pragma unroll
    for (int l = 0; l < 2; ++l) {
      int s = tid + l * 256;
      int r = s >> 2, kq = s & 3;
      int gr = bm + r, gk = k0 + kq * 4;
      float4 v = make_float4(0.f, 0.f, 0.f, 0.f);
      if (gr < M && gk < K)
        v = *reinterpret_cast<const float4*>(&A[(size_t)gr * lda + gk]);
      As[kq * 4 + 0][r] = v.x; As[kq * 4 + 1][r] = v.y;
      As[kq * 4 + 2][r] = v.z; As[kq * 4 + 3][r] = v.w;
    }
    if (TRANSB) {
#pragma unroll
      for (int l = 0; l < 2; ++l) {
        int s = tid + l * 256;
        int c = s >> 2, kq = s & 3;
        int gc = bn + c, gk = k0 + kq * 4;
        float4 v = make_float4(0.f, 0.f, 0.f, 0.f);
        if (gc < N && gk < K)
          v = *reinterpret_cast<const float4*>(&B[(size_t)gc * ldb + gk]);
        Bs[kq * 4 + 0][c] = v.x; Bs[kq * 4 + 1][c] = v.y;
        Bs[kq * 4 + 2][c] = v.z; Bs[kq * 4 + 3][c] = v.w;
      }
    } else {
#pragma unroll
      for (int l = 0; l < 8; ++l) {
        int s = tid + l * 256;
        int kk = s >> 7, c = s & 127;
        int gk = k0 + kk, gc = bn + c;
        Bs[kk][c] = (gk < K && gc < N) ? B[(size_t)gk * ldb + gc] : 0.f;
      }
    }
    __syncthreads();
#pragma unroll
    for (int kk = 0; kk < 16; ++kk) {
      float4 a0 = *reinterpret_cast<const float4*>(&As[kk][ty * 8]);
      float4 a1 = *reinterpret_cast<const float4*>(&As[kk][ty * 8 + 4]);
      float4 b0 = *reinterpret_cast<const float4*>(&Bs[kk][tx * 8]);
      float4 b1 = *reinterpret_cast<const float4*>(&Bs[kk][tx * 8 + 4]);
      float av[8] = {a0.x, a0.y, a0.z, a0.w, a1.x, a1.y, a1.z, a1.w};
      float bv[8] = {b0.x, b0.y, b0.z, b0.w, b1.x, b1.y, b1.z, b1.w};
#pragma unroll
      for (int i = 0; i < 8; ++i)
#pragma unroll
        for (int j = 0; j < 8; ++j)
          acc[i][j] += av[i] * bv[j];
    }
    __syncthreads();
  }
#pragma unroll
  for (int i = 0; i < 8; ++i) {
    int gr = bm + ty * 8 + i;
    if (gr >= M) continue;
#pragma unroll
    for (int j = 0; j < 8; ++j) {
      int gc = bn + tx * 8 + j;
      if (gc >= N) continue;
      float v = acc[i][j];
      if (ADD_BIAS) v += bias[gc];
      if (RELU) v = fmaxf(v, 0.f);
      C[(size_t)gr * ldc + gc] = v;
    }
  }
}

// ---------------- fused persistent GRU ----------------
// Block = 64 nodes, 4 waves. Column-split: wave w owns gate-cols [32w,32w+32)
// for r,z,n jointly (gates lane-local). Weights live in REGISTERS (36 B-frags,
// loaded once — kills the 900MB of per-step weight refetch). h double-buffered
// in LDS (bf16, XOR-swizzled); xt staged per step.
__global__ __launch_bounds__(256, 1) void gru_fused_k(
    const int* __restrict__ xtext, const float* __restrict__ embed,
    const unsigned short* __restrict__ wihB, const unsigned short* __restrict__ whhB,
    const float* __restrict__ brz, const float* __restrict__ binv, const float* __restrict__ bhnv,
    float* __restrict__ txt)
{
  __shared__ unsigned char hs[2][64 * 256]; // h bf16 [64][128], swizzled, dbuf
  __shared__ unsigned char xs[64 * 128];    // xt bf16 [64][64], swizzled
  const int tid = threadIdx.x;
  const int n0 = blockIdx.x * 64;
  const int wid = tid >> 6, lane = tid & 63;
  const int l16 = lane & 15, lk = lane >> 4;

  for (int i = tid; i < 64 * 256 / 4; i += 256) ((unsigned int*)hs[0])[i] = 0u;

  // ---- preload weight B-frags into registers (step-invariant) ----
  short8v wR[2][2], wZ[2][2], wN[2][2]; // wih [cf][ks]
  short8v uR[2][4], uZ[2][4], uN[2][4]; // whh [cf][ks]
  float bRr[2], bZr[2], bIr[2], bHr[2];
#pragma unroll
  for (int cf = 0; cf < 2; ++cf) {
    int col = wid * 32 + cf * 16 + l16;
#pragma unroll
    for (int ks = 0; ks < 2; ++ks) {
      wR[cf][ks] = *reinterpret_cast<const short8v*>(&wihB[(col      ) * 64 + ks * 32 + lk * 8]);
      wZ[cf][ks] = *reinterpret_cast<const short8v*>(&wihB[(col + 128) * 64 + ks * 32 + lk * 8]);
      wN[cf][ks] = *reinterpret_cast<const short8v*>(&wihB[(col + 256) * 64 + ks * 32 + lk * 8]);
    }
#pragma unroll
    for (int ks = 0; ks < 4; ++ks) {
      uR[cf][ks] = *reinterpret_cast<const short8v*>(&whhB[(col      ) * 128 + ks * 32 + lk * 8]);
      uZ[cf][ks] = *reinterpret_cast<const short8v*>(&whhB[(col + 128) * 128 + ks * 32 + lk * 8]);
      uN[cf][ks] = *reinterpret_cast<const short8v*>(&whhB[(col + 256) * 128 + ks * 32 + lk * 8]);
    }
    bRr[cf] = brz[col]; bZr[cf] = brz[128 + col];
    bIr[cf] = binv[col]; bHr[cf] = bhnv[col];
  }

  f32x4 txtacc[4][2];
#pragma unroll
  for (int mf = 0; mf < 4; ++mf)
#pragma unroll
    for (int cf = 0; cf < 2; ++cf) txtacc[mf][cf] = f32x4{0.f, 0.f, 0.f, 0.f};

  int cur = 0;
  for (int t = 0; t < LL; ++t) {
    __syncthreads();
    { // stage xt tile
      const int k4 = tid & 15, r0 = tid >> 4;
#pragma unroll
      for (int rep = 0; rep < 4; ++rep) {
        int row = r0 + rep * 16;
        int n = n0 + row; if (n >= NN) n = NN - 1;
        int tok = xtext[n * LL + t];
        float4 v = *reinterpret_cast<const float4*>(&embed[(size_t)tok * TT + k4 * 4]);
        ushort4 w;
        w.x = f32_to_bf16(v.x); w.y = f32_to_bf16(v.y);
        w.z = f32_to_bf16(v.z); w.w = f32_to_bf16(v.w);
        *reinterpret_cast<ushort4*>(&xs[row * 128 + ((k4 * 8) ^ ((row & 7) << 4))]) = w;
      }
    }
    __syncthreads();

#pragma unroll
    for (int mf = 0; mf < 4; ++mf) {
      const int arow = mf * 16 + l16;
      const int asw = (arow & 7) << 4;
      short8v ax[2], ah[4];
#pragma unroll
      for (int ks = 0; ks < 2; ++ks)
        ax[ks] = *reinterpret_cast<const short8v*>(&xs[arow * 128 + ((ks * 64 + lk * 16) ^ asw)]);
#pragma unroll
      for (int ks = 0; ks < 4; ++ks)
        ah[ks] = *reinterpret_cast<const short8v*>(&hs[cur][arow * 256 + ((ks * 64 + lk * 16) ^ asw)]);

      f32x4 aR[2], aZ[2], aI[2], aHn[2];
#pragma unroll
      for (int cf = 0; cf < 2; ++cf) {
        aR[cf] = f32x4{0.f, 0.f, 0.f, 0.f}; aZ[cf] = f32x4{0.f, 0.f, 0.f, 0.f};
        aI[cf] = f32x4{0.f, 0.f, 0.f, 0.f}; aHn[cf] = f32x4{0.f, 0.f, 0.f, 0.f};
#pragma unroll
        for (int ks = 0; ks < 2; ++ks) {
          aR[cf] = MFMA_BF16(ax[ks], wR[cf][ks], aR[cf]);
          aZ[cf] = MFMA_BF16(ax[ks], wZ[cf][ks], aZ[cf]);
          aI[cf] = MFMA_BF16(ax[ks], wN[cf][ks], aI[cf]);
        }
#pragma unroll
        for (int ks = 0; ks < 4; ++ks) {
          aR[cf]  = MFMA_BF16(ah[ks], uR[cf][ks], aR[cf]);
          aZ[cf]  = MFMA_BF16(ah[ks], uZ[cf][ks], aZ[cf]);
          aHn[cf] = MFMA_BF16(ah[ks], uN[cf][ks], aHn[cf]);
        }
      }

      // gates (lane-local): row = mf*16 + lk*4 + reg, col = wid*32 + cf*16 + l16
#pragma unroll
      for (int cf = 0; cf < 2; ++cf) {
        const int j = wid * 32 + cf * 16 + l16;
#pragma unroll
        for (int reg = 0; reg < 4; ++reg) {
          const int row = mf * 16 + lk * 4 + reg;
          const int byte = row * 256 + ((j * 2) ^ ((row & 7) << 4));
          float hold = bf16_to_f32(*reinterpret_cast<unsigned short*>(&hs[cur][byte]));
          float rg = fast_sigmoid(aR[cf][reg] + bRr[cf]);
          float zg = fast_sigmoid(aZ[cf][reg] + bZr[cf]);
          float ng = fast_tanh(aI[cf][reg] + bIr[cf] + rg * (aHn[cf][reg] + bHr[cf]));
          float h2 = (1.f - zg) * ng + zg * hold;
          txtacc[mf][cf][reg] += h2;
          *reinterpret_cast<unsigned short*>(&hs[cur ^ 1][byte]) = f32_to_bf16(h2);
        }
      }
    }
    cur ^= 1;
  }

#pragma unroll
  for (int mf = 0; mf < 4; ++mf)
#pragma unroll
    for (int cf = 0; cf < 2; ++cf) {
      const int j = wid * 32 + cf * 16 + l16;
#pragma unroll
      for (int reg = 0; reg < 4; ++reg) {
        const int row = mf * 16 + lk * 4 + reg;
        const int n = n0 + row;
        if (n < NN) txt[(size_t)n * HH + j] = txtacc[mf][cf][reg];
      }
    }
}

// ---------------- fused edge heads via MFMA ----------------
__global__ __launch_bounds__(256) void edge_mfma_k(
    const int* __restrict__ eidx,
    const float* __restrict__ Ap, const float* __restrict__ Bp,
    const float* __restrict__ At, const float* __restrict__ Bt,
    const float* __restrict__ Ai, const float* __restrict__ Bi,
    const unsigned short* __restrict__ rw1T, const float* __restrict__ rb1,
    const float* __restrict__ rw2, const float* __restrict__ rb2,
    const unsigned short* __restrict__ cw1T, const float* __restrict__ cb1,
    const float* __restrict__ cw2, const float* __restrict__ cb2,
    float* __restrict__ out)
{
  __shared__ unsigned char es[128 * 128];
  __shared__ int sd[2][128];
  const int tid = threadIdx.x;
  const int e0 = blockIdx.x * 128;
  const int wid = tid >> 6, lane = tid & 63;
  const int l16 = lane & 15, lk = lane >> 4;
  const int wr = wid * 32;

  if (tid < 128) { sd[0][tid] = eidx[e0 + tid]; sd[1][tid] = eidx[NE + e0 + tid]; }

  f32x4 acc[2][2][8];
#pragma unroll
  for (int h = 0; h < 2; ++h)
#pragma unroll
    for (int mf = 0; mf < 2; ++mf)
#pragma unroll
      for (int nf = 0; nf < 8; ++nf) acc[h][mf][nf] = f32x4{0.f, 0.f, 0.f, 0.f};

#pragma unroll
  for (int c = 0; c < 6; ++c) {
    const float* Asrc = (c < 2 ? Ap : c < 4 ? At : Ai) + (c & 1) * 64;
    const float* Bsrc = (c < 2 ? Bp : c < 4 ? Bt : Bi) + (c & 1) * 64;
    __syncthreads();
    {
      int k4 = tid & 15, el0 = tid >> 4;
#pragma unroll
      for (int rep = 0; rep < 8; ++rep) {
        int el = el0 + rep * 16;
        int s = sd[0][el], d = sd[1][el];
        float4 va = *reinterpret_cast<const float4*>(&Asrc[(size_t)s * HH + k4 * 4]);
        float4 vb = *reinterpret_cast<const float4*>(&Bsrc[(size_t)d * HH + k4 * 4]);
        ushort4 w;
        w.x = f32_to_bf16(fmaxf(va.x + vb.x, 0.f));
        w.y = f32_to_bf16(fmaxf(va.y + vb.y, 0.f));
        w.z = f32_to_bf16(fmaxf(va.z + vb.z, 0.f));
        w.w = f32_to_bf16(fmaxf(va.w + vb.w, 0.f));
        *reinterpret_cast<ushort4*>(&es[el * 128 + ((k4 * 8) ^ ((el & 7) << 4))]) = w;
      }
    }
    __syncthreads();
#pragma unroll
    for (int ks = 0; ks < 2; ++ks) {
      short8v a[2];
#pragma unroll
      for (int mf = 0; mf < 2; ++mf) {
        int row = wr + mf * 16 + l16;
        a[mf] = *reinterpret_cast<const short8v*>(&es[row * 128 + ((ks * 64 + lk * 16) ^ ((row & 7) << 4))]);
      }
      int kglob = c * 64 + ks * 32 + lk * 8;
#pragma unroll
      for (int h = 0; h < 2; ++h) {
        const unsigned short* w1T = h ? cw1T : rw1T;
#pragma unroll
        for (int nf = 0; nf < 8; ++nf) {
          int col = nf * 16 + l16;
          short8v b = *reinterpret_cast<const short8v*>(&w1T[(size_t)col * 384 + kglob]);
          acc[h][0][nf] = MFMA_BF16(a[0], b, acc[h][0][nf]);
          acc[h][1][nf] = MFMA_BF16(a[1], b, acc[h][1][nf]);
        }
      }
    }
  }

#pragma unroll
  for (int h = 0; h < 2; ++h) {
    const float* b1 = h ? cb1 : rb1;
    const float* w2 = h ? cw2 : rw2;
    const float* b2 = h ? cb2 : rb2;
#pragma unroll
    for (int mf = 0; mf < 2; ++mf) {
#pragma unroll
      for (int reg = 0; reg < 4; ++reg) {
        float p0 = 0.f, p1 = 0.f;
#pragma unroll
        for (int nf = 0; nf < 8; ++nf) {
          int col = nf * 16 + l16;
          float hv = fmaxf(acc[h][mf][nf][reg] + b1[col], 0.f);
          p0 += hv * w2[col * 2];
          p1 += hv * w2[col * 2 + 1];
        }
#pragma unroll
        for (int m = 1; m < 16; m <<= 1) {
          p0 += __shfl_xor(p0, m);
          p1 += __shfl_xor(p1, m);
        }
        if (l16 == 0) {
          float l0 = p0 + b2[0], l1 = p1 + b2[1];
          float mx = fmaxf(l0, l1);
          float lse = mx + __logf(__expf(l0 - mx) + __expf(l1 - mx));
          int edge = e0 + wr + mf * 16 + lk * 4 + reg;
          float2 o2 = make_float2(l0 - lse, l1 - lse);
          *reinterpret_cast<float2*>(&out[(size_t)h * 2 * NE + (size_t)edge * 2]) = o2;
        }
      }
    }
  }
}

// ---------------- launch ----------------
extern "C" void kernel_launch(void* const* d_in, const int* in_sizes, int n_in,
                              void* d_out, int out_size, void* d_ws, size_t ws_size,
                              hipStream_t stream)
{
  const float* x       = (const float*)d_in[0];
  const int*   eidx    = (const int*)  d_in[1];
  const int*   xtext   = (const int*)  d_in[2];
  const float* imgf    = (const float*)d_in[3];
  const float* conv1_w = (const float*)d_in[4];
  const float* conv1_b = (const float*)d_in[5];
  const float* conv2_w = (const float*)d_in[6];
  const float* conv2_b = (const float*)d_in[7];
  const float* embed   = (const float*)d_in[8];
  const float* gwih    = (const float*)d_in[9];
  const float* gwhh    = (const float*)d_in[10];
  const float* gbih    = (const float*)d_in[11];
  const float* gbhh    = (const float*)d_in[12];
  const float* lpw     = (const float*)d_in[13];
  const float* lpb     = (const float*)d_in[14];
  const float* ltw     = (const float*)d_in[15];
  const float* ltb     = (const float*)d_in[16];
  const float* liw     = (const float*)d_in[17];
  const float* lib     = (const float*)d_in[18];
  const float* rw1     = (const float*)d_in[19];
  const float* rb1     = (const float*)d_in[20];
  const float* rw2     = (const float*)d_in[21];
  const float* rb2     = (const float*)d_in[22];
  const float* cw1     = (const float*)d_in[23];
  const float* cb1     = (const float*)d_in[24];
  const float* cw2     = (const float*)d_in[25];
  const float* cb2     = (const float*)d_in[26];
  float* out = (float*)d_out;

  float* wsf = (float*)d_ws;
  size_t o = 0;
  auto alloc = [&](size_t n) { float* p = wsf + o; o += n; return p; };
  float* xw   = alloc((size_t)NN * HH);
  float* agg  = alloc((size_t)NN * HH);
  float* pos  = alloc((size_t)NN * HH);
  float* txt  = alloc((size_t)NN * HH);
  float* dinv = alloc(NN);
  float* Ap = alloc((size_t)NN * HH);
  float* Bp = alloc((size_t)NN * HH);
  float* At = alloc((size_t)NN * HH);
  float* Bt = alloc((size_t)NN * HH);
  float* Ai = alloc((size_t)NN * HH);
  float* Bi = alloc((size_t)NN * HH);
  unsigned short* wihB = (unsigned short*)alloc(384 * 64 / 2);
  unsigned short* whhB = (unsigned short*)alloc(384 * 128 / 2);
  unsigned short* rw1T = (unsigned short*)alloc(384 * 128 / 2);
  unsigned short* cw1T = (unsigned short*)alloc(384 * 128 / 2);
  float* brz  = alloc(256);
  float* binv = alloc(128);
  float* bhnv = alloc(128);

  dim3 b256(256);
  auto cdiv = [](int a, int b) { return (a + b - 1) / b; };
  const int MB = cdiv(NN, 128); // 157

  cvt_bf16_k<<<cdiv(384 * 64, 256), b256, 0, stream>>>(gwih, wihB, 384 * 64);
  cvt_bf16_k<<<cdiv(384 * 128, 256), b256, 0, stream>>>(gwhh, whhB, 384 * 128);
  transpose_bf16_k<<<cdiv(384 * 128, 256), b256, 0, stream>>>(rw1, rw1T, 384, 128);
  transpose_bf16_k<<<cdiv(384 * 128, 256), b256, 0, stream>>>(cw1, cw1T, 384, 128);
  gru_bias_k<<<2, b256, 0, stream>>>(gbih, gbhh, brz, binv, bhnv);

  fill_zero_k<<<cdiv(NN, 256), b256, 0, stream>>>(dinv, NN);
  deg_k<<<cdiv(NE, 256), b256, 0, stream>>>(eidx, dinv);
  dinv_k<<<cdiv(NN, 256), b256, 0, stream>>>(dinv);

  gemm_k<false, false, false><<<dim3(1, MB), b256, 0, stream>>>(x, conv1_w, nullptr, xw, NN, 128, 8, 8, 128, 128);
  fill_zero_k<<<cdiv(NN * HH, 256), b256, 0, stream>>>(agg, NN * HH);
  gcn_agg_k<<<NE / 4, b256, 0, stream>>>(eidx, xw, dinv, agg);
  gcn_fin_k<<<cdiv(NN * HH, 256), b256, 0, stream>>>(agg, xw, dinv, conv1_b, pos);
  gemm_k<false, false, false><<<dim3(1, MB), b256, 0, stream>>>(pos, conv2_w, nullptr, xw, NN, 128, 128, 128, 128, 128);
  fill_zero_k<<<cdiv(NN * HH, 256), b256, 0, stream>>>(agg, NN * HH);
  gcn_agg_k<<<NE / 4, b256, 0, stream>>>(eidx, xw, dinv, agg);
  gcn_fin_k<<<cdiv(NN * HH, 256), b256, 0, stream>>>(agg, xw, dinv, conv2_b, pos);

  gru_fused_k<<<cdiv(NN, 64), b256, 0, stream>>>(xtext, embed, wihB, whhB, brz, binv, bhnv, txt);

  gemm_k<false, false, false><<<dim3(1, MB), b256, 0, stream>>>(pos,  lpw,           nullptr, Ap, NN, 128, 128, 128, 128, 128);
  gemm_k<false, true,  false><<<dim3(1, MB), b256, 0, stream>>>(pos,  lpw + 128*128, lpb,     Bp, NN, 128, 128, 128, 128, 128);
  gemm_k<false, false, false><<<dim3(1, MB), b256, 0, stream>>>(txt,  ltw,           nullptr, At, NN, 128, 128, 128, 128, 128);
  gemm_k<false, true,  false><<<dim3(1, MB), b256, 0, stream>>>(txt,  ltw + 128*128, ltb,     Bt, NN, 128, 128, 128, 128, 128);
  gemm_k<false, false, false><<<dim3(1, MB), b256, 0, stream>>>(imgf, liw,           nullptr, Ai, NN, 128, 256, 256, 128, 128);
  gemm_k<false, true,  false><<<dim3(1, MB), b256, 0, stream>>>(imgf, liw + 256*128, lib,     Bi, NN, 128, 256, 256, 128, 128);

  edge_mfma_k<<<NE / 128, b256, 0, stream>>>(eidx, Ap, Bp, At, Bt, Ai, Bi,
                                             rw1T, rb1, rw2, rb2, cw1T, cb1, cw2, cb2, out);
}

// Round 4
// 1035.296 us; speedup vs baseline: 4.5579x; 1.4641x over previous
//
#include <hip/hip_runtime.h>
#include <hip/hip_bf16.h>

#define NN 20000
#define NE 320000
#define LL 16
#define TT 64
#define HH 128

typedef __attribute__((ext_vector_type(8))) short short8v;
typedef __attribute__((ext_vector_type(4))) float f32x4;
#define MFMA_BF16(a,b,c) __builtin_amdgcn_mfma_f32_16x16x32_bf16(a,b,c,0,0,0)

__device__ inline unsigned short f32_to_bf16(float v) {
  unsigned int b = __float_as_uint(v);
  b += 0x7fffu + ((b >> 16) & 1u);
  return (unsigned short)(b >> 16);
}
__device__ inline float bf16_to_f32(unsigned short u) {
  return __uint_as_float(((unsigned int)u) << 16);
}
__device__ inline float fast_sigmoid(float x) {
  return __builtin_amdgcn_rcpf(1.f + __expf(-x));
}
__device__ inline float fast_tanh(float x) {
  float e = __expf(2.f * x);
  return 1.f - 2.f * __builtin_amdgcn_rcpf(e + 1.f);
}
__device__ inline unsigned int cvt_pk_bf16(float lo, float hi) {
  unsigned int r;
  asm("v_cvt_pk_bf16_f32 %0, %1, %2" : "=v"(r) : "v"(lo), "v"(hi));
  return r;
}
// unpack 2 bf16 from us/ud, add, relu, repack
__device__ inline unsigned int combine2(unsigned int us, unsigned int ud) {
  float sl = __uint_as_float(us << 16);
  float sh = __uint_as_float(us & 0xffff0000u);
  float dl = __uint_as_float(ud << 16);
  float dh = __uint_as_float(ud & 0xffff0000u);
  return cvt_pk_bf16(fmaxf(sl + dl, 0.f), fmaxf(sh + dh, 0.f));
}

// ---------------- small utility kernels ----------------
__global__ void fill_zero_k(float* __restrict__ p, int n) {
  int i = blockIdx.x * 256 + threadIdx.x;
  if (i < n) p[i] = 0.f;
}

__global__ void deg_k(const int* __restrict__ eidx, float* __restrict__ deg) {
  int e = blockIdx.x * 256 + threadIdx.x;
  if (e < NE) atomicAdd(&deg[eidx[NE + e]], 1.f);
}

__global__ void dinv_k(float* __restrict__ deg) {
  int i = blockIdx.x * 256 + threadIdx.x;
  if (i < NN) deg[i] = rsqrtf(deg[i] + 1.f);
}

__global__ void gcn_agg_k(const int* __restrict__ eidx, const float* __restrict__ xw,
                          const float* __restrict__ dinv, float* __restrict__ agg) {
  int e = blockIdx.x * 4 + (threadIdx.x >> 6);
  int lane = threadIdx.x & 63;
  if (e >= NE) return;
  int s = eidx[e], d = eidx[NE + e];
  float nrm = dinv[s] * dinv[d];
  atomicAdd(&agg[d * HH + lane],      xw[s * HH + lane] * nrm);
  atomicAdd(&agg[d * HH + 64 + lane], xw[s * HH + 64 + lane] * nrm);
}

// GCN finalize -> bf16 node features
__global__ void gcn_fin_k(const float* __restrict__ agg, const float* __restrict__ xw,
                          const float* __restrict__ dinv, const float* __restrict__ b,
                          unsigned short* __restrict__ out) {
  int i = blockIdx.x * 256 + threadIdx.x;
  if (i >= NN * HH) return;
  int n = i >> 7, h = i & 127;
  float di = dinv[n];
  out[i] = f32_to_bf16(fmaxf(agg[i] + xw[i] * di * di + b[h], 0.f));
}

__global__ void cvt_bf16_k(const float* __restrict__ in, unsigned short* __restrict__ out, int n) {
  int i = blockIdx.x * 256 + threadIdx.x;
  if (i < n) out[i] = f32_to_bf16(in[i]);
}

// in[R][C] -> out[C][R] bf16
__global__ void transpose_bf16_k(const float* __restrict__ in, unsigned short* __restrict__ out,
                                 int R, int C) {
  int i = blockIdx.x * 256 + threadIdx.x;
  if (i >= R * C) return;
  int c = i / R, r = i - c * R;
  out[i] = f32_to_bf16(in[r * C + c]);
}

__global__ void gru_bias_k(const float* __restrict__ bih, const float* __restrict__ bhh,
                           float* __restrict__ brz, float* __restrict__ binv, float* __restrict__ bhnv) {
  int i = blockIdx.x * 256 + threadIdx.x;
  if (i < 256) brz[i] = bih[i] + bhh[i];
  else if (i < 384) binv[i - 256] = bih[i];
  else if (i < 512) bhnv[i - 384] = bhh[i - 128];
}

// combined table weight: wt[col][k], col in [0,256); col<128 -> top half, else bottom
__global__ void pack_tblw_k(const float* __restrict__ w, unsigned short* __restrict__ wt, int K) {
  int i = blockIdx.x * 256 + threadIdx.x;
  if (i >= 256 * K) return;
  int col = i / K, k = i - col * K;
  float v = (col < 128) ? w[k * 128 + col] : w[(K + k) * 128 + (col - 128)];
  wt[i] = f32_to_bf16(v);
}

__global__ void pack_bias_k(const float* __restrict__ bp, const float* __restrict__ bt,
                            const float* __restrict__ bi, float* __restrict__ bc) {
  int i = blockIdx.x * 256 + threadIdx.x;
  if (i >= 768) return;
  int t = i >> 8, j = i & 255;
  const float* b = t == 0 ? bp : t == 1 ? bt : bi;
  bc[i] = (j < 128) ? 0.f : b[j - 128];
}

// ---------------- generic tiled f32 GEMM (conv1 only, K=8) ----
template<bool TRANSB, bool ADD_BIAS, bool RELU>
__global__ __launch_bounds__(256) void gemm_k(
    const float* __restrict__ A, const float* __restrict__ B,
    const float* __restrict__ bias, float* __restrict__ C,
    int M, int N, int K, int lda, int ldb, int ldc)
{
  __shared__ float As[16][132];
  __shared__ float Bs[16][132];
  int tid = threadIdx.x;
  int bm = blockIdx.y * 128, bn = blockIdx.x * 128;
  int tx = tid & 15, ty = tid >> 4;
  float acc[8][8];
#pragma unroll
  for (int i = 0; i < 8; ++i)
#pragma unroll
    for (int j = 0; j < 8; ++j) acc[i][j] = 0.f;

  for (int k0 = 0; k0 < K; k0 += 16) {
#pragma unroll
    for (int l = 0; l < 2; ++l) {
      int s = tid + l * 256;
      int r = s >> 2, kq = s & 3;
      int gr = bm + r, gk = k0 + kq * 4;
      float4 v = make_float4(0.f, 0.f, 0.f, 0.f);
      if (gr < M && gk < K)
        v = *reinterpret_cast<const float4*>(&A[(size_t)gr * lda + gk]);
      As[kq * 4 + 0][r] = v.x; As[kq * 4 + 1][r] = v.y;
      As[kq * 4 + 2][r] = v.z; As[kq * 4 + 3][r] = v.w;
    }
#pragma unroll
    for (int l = 0; l < 8; ++l) {
      int s = tid + l * 256;
      int kk = s >> 7, c = s & 127;
      int gk = k0 + kk, gc = bn + c;
      Bs[kk][c] = (gk < K && gc < N) ? B[(size_t)gk * ldb + gc] : 0.f;
    }
    __syncthreads();
#pragma unroll
    for (int kk = 0; kk < 16; ++kk) {
      float4 a0 = *reinterpret_cast<const float4*>(&As[kk][ty * 8]);
      float4 a1 = *reinterpret_cast<const float4*>(&As[kk][ty * 8 + 4]);
      float4 b0 = *reinterpret_cast<const float4*>(&Bs[kk][tx * 8]);
      float4 b1 = *reinterpret_cast<const float4*>(&Bs[kk][tx * 8 + 4]);
      float av[8] = {a0.x, a0.y, a0.z, a0.w, a1.x, a1.y, a1.z, a1.w};
      float bv[8] = {b0.x, b0.y, b0.z, b0.w, b1.x, b1.y, b1.z, b1.w};
#pragma unroll
      for (int i = 0; i < 8; ++i)
#pragma unroll
        for (int j = 0; j < 8; ++j)
          acc[i][j] += av[i] * bv[j];
    }
    __syncthreads();
  }
#pragma unroll
  for (int i = 0; i < 8; ++i) {
    int gr = bm + ty * 8 + i;
    if (gr >= M) continue;
#pragma unroll
    for (int j = 0; j < 8; ++j) {
      int gc = bn + tx * 8 + j;
      if (gc >= N) continue;
      float v = acc[i][j];
      if (ADD_BIAS) v += bias[gc];
      if (RELU) v = fmaxf(v, 0.f);
      C[(size_t)gr * ldc + gc] = v;
    }
  }
}

// ---------------- direct-fragment MFMA GEMM (bf16 A, bf16 WT[col][K]) --------
// block 256 = 4 waves; tile 128 rows x 128 cols; wave = 32 rows x 128 cols.
template<int KDIM, int NCOLS, bool OUTBF16, bool ADDBIAS>
__global__ __launch_bounds__(256) void gemm_mfma_k(
    const unsigned short* __restrict__ A, const unsigned short* __restrict__ WT,
    const float* __restrict__ bias, void* __restrict__ Cv, int M)
{
  const int tid = threadIdx.x;
  const int wid = tid >> 6, lane = tid & 63;
  const int l16 = lane & 15, lk = lane >> 4;
  const int bm = blockIdx.x * 128, bn = blockIdx.y * 128;
  const int wr = wid * 32;

  int row[2];
#pragma unroll
  for (int mf = 0; mf < 2; ++mf) {
    int r = bm + wr + mf * 16 + l16;
    row[mf] = r < M ? r : M - 1;
  }
  f32x4 acc[2][8];
#pragma unroll
  for (int mf = 0; mf < 2; ++mf)
#pragma unroll
    for (int nf = 0; nf < 8; ++nf) acc[mf][nf] = f32x4{0.f, 0.f, 0.f, 0.f};

#pragma unroll
  for (int kc = 0; kc < KDIM / 32; ++kc) {
    short8v a[2];
#pragma unroll
    for (int mf = 0; mf < 2; ++mf)
      a[mf] = *reinterpret_cast<const short8v*>(&A[(size_t)row[mf] * KDIM + kc * 32 + lk * 8]);
#pragma unroll
    for (int nf = 0; nf < 8; ++nf) {
      int col = bn + nf * 16 + l16;
      short8v b = *reinterpret_cast<const short8v*>(&WT[(size_t)col * KDIM + kc * 32 + lk * 8]);
      acc[0][nf] = MFMA_BF16(a[0], b, acc[0][nf]);
      acc[1][nf] = MFMA_BF16(a[1], b, acc[1][nf]);
    }
  }
#pragma unroll
  for (int mf = 0; mf < 2; ++mf)
#pragma unroll
    for (int nf = 0; nf < 8; ++nf) {
      int col = bn + nf * 16 + l16;
      float bb = ADDBIAS ? bias[col] : 0.f;
#pragma unroll
      for (int reg = 0; reg < 4; ++reg) {
        int r = bm + wr + mf * 16 + lk * 4 + reg;
        if (r < M) {
          float v = acc[mf][nf][reg] + bb;
          if (OUTBF16) ((unsigned short*)Cv)[(size_t)r * NCOLS + col] = f32_to_bf16(v);
          else         ((float*)Cv)[(size_t)r * NCOLS + col] = v;
        }
      }
    }
}

// ---------------- fused persistent GRU (weights in registers) --------
__global__ __launch_bounds__(256, 1) void gru_fused_k(
    const int* __restrict__ xtext, const float* __restrict__ embed,
    const unsigned short* __restrict__ wihB, const unsigned short* __restrict__ whhB,
    const float* __restrict__ brz, const float* __restrict__ binv, const float* __restrict__ bhnv,
    unsigned short* __restrict__ txt)
{
  __shared__ unsigned char hs[2][64 * 256]; // h bf16 [64][128], swizzled, dbuf
  __shared__ unsigned char xs[64 * 128];    // xt bf16 [64][64], swizzled
  const int tid = threadIdx.x;
  const int n0 = blockIdx.x * 64;
  const int wid = tid >> 6, lane = tid & 63;
  const int l16 = lane & 15, lk = lane >> 4;

  for (int i = tid; i < 64 * 256 / 4; i += 256) ((unsigned int*)hs[0])[i] = 0u;

  short8v wR[2][2], wZ[2][2], wN[2][2];
  short8v uR[2][4], uZ[2][4], uN[2][4];
  float bRr[2], bZr[2], bIr[2], bHr[2];
#pragma unroll
  for (int cf = 0; cf < 2; ++cf) {
    int col = wid * 32 + cf * 16 + l16;
#pragma unroll
    for (int ks = 0; ks < 2; ++ks) {
      wR[cf][ks] = *reinterpret_cast<const short8v*>(&wihB[(col      ) * 64 + ks * 32 + lk * 8]);
      wZ[cf][ks] = *reinterpret_cast<const short8v*>(&wihB[(col + 128) * 64 + ks * 32 + lk * 8]);
      wN[cf][ks] = *reinterpret_cast<const short8v*>(&wihB[(col + 256) * 64 + ks * 32 + lk * 8]);
    }
#pragma unroll
    for (int ks = 0; ks < 4; ++ks) {
      uR[cf][ks] = *reinterpret_cast<const short8v*>(&whhB[(col      ) * 128 + ks * 32 + lk * 8]);
      uZ[cf][ks] = *reinterpret_cast<const short8v*>(&whhB[(col + 128) * 128 + ks * 32 + lk * 8]);
      uN[cf][ks] = *reinterpret_cast<const short8v*>(&whhB[(col + 256) * 128 + ks * 32 + lk * 8]);
    }
    bRr[cf] = brz[col]; bZr[cf] = brz[128 + col];
    bIr[cf] = binv[col]; bHr[cf] = bhnv[col];
  }

  f32x4 txtacc[4][2];
#pragma unroll
  for (int mf = 0; mf < 4; ++mf)
#pragma unroll
    for (int cf = 0; cf < 2; ++cf) txtacc[mf][cf] = f32x4{0.f, 0.f, 0.f, 0.f};

  int cur = 0;
  for (int t = 0; t < LL; ++t) {
    __syncthreads();
    {
      const int k4 = tid & 15, r0 = tid >> 4;
#pragma unroll
      for (int rep = 0; rep < 4; ++rep) {
        int row = r0 + rep * 16;
        int n = n0 + row; if (n >= NN) n = NN - 1;
        int tok = xtext[n * LL + t];
        float4 v = *reinterpret_cast<const float4*>(&embed[(size_t)tok * TT + k4 * 4]);
        ushort4 w;
        w.x = f32_to_bf16(v.x); w.y = f32_to_bf16(v.y);
        w.z = f32_to_bf16(v.z); w.w = f32_to_bf16(v.w);
        *reinterpret_cast<ushort4*>(&xs[row * 128 + ((k4 * 8) ^ ((row & 7) << 4))]) = w;
      }
    }
    __syncthreads();

#pragma unroll
    for (int mf = 0; mf < 4; ++mf) {
      const int arow = mf * 16 + l16;
      const int asw = (arow & 7) << 4;
      short8v ax[2], ah[4];
#pragma unroll
      for (int ks = 0; ks < 2; ++ks)
        ax[ks] = *reinterpret_cast<const short8v*>(&xs[arow * 128 + ((ks * 64 + lk * 16) ^ asw)]);
#pragma unroll
      for (int ks = 0; ks < 4; ++ks)
        ah[ks] = *reinterpret_cast<const short8v*>(&hs[cur][arow * 256 + ((ks * 64 + lk * 16) ^ asw)]);

      f32x4 aR[2], aZ[2], aI[2], aHn[2];
#pragma unroll
      for (int cf = 0; cf < 2; ++cf) {
        aR[cf] = f32x4{0.f, 0.f, 0.f, 0.f}; aZ[cf] = f32x4{0.f, 0.f, 0.f, 0.f};
        aI[cf] = f32x4{0.f, 0.f, 0.f, 0.f}; aHn[cf] = f32x4{0.f, 0.f, 0.f, 0.f};
#pragma unroll
        for (int ks = 0; ks < 2; ++ks) {
          aR[cf] = MFMA_BF16(ax[ks], wR[cf][ks], aR[cf]);
          aZ[cf] = MFMA_BF16(ax[ks], wZ[cf][ks], aZ[cf]);
          aI[cf] = MFMA_BF16(ax[ks], wN[cf][ks], aI[cf]);
        }
#pragma unroll
        for (int ks = 0; ks < 4; ++ks) {
          aR[cf]  = MFMA_BF16(ah[ks], uR[cf][ks], aR[cf]);
          aZ[cf]  = MFMA_BF16(ah[ks], uZ[cf][ks], aZ[cf]);
          aHn[cf] = MFMA_BF16(ah[ks], uN[cf][ks], aHn[cf]);
        }
      }

#pragma unroll
      for (int cf = 0; cf < 2; ++cf) {
        const int j = wid * 32 + cf * 16 + l16;
#pragma unroll
        for (int reg = 0; reg < 4; ++reg) {
          const int row = mf * 16 + lk * 4 + reg;
          const int byte = row * 256 + ((j * 2) ^ ((row & 7) << 4));
          float hold = bf16_to_f32(*reinterpret_cast<unsigned short*>(&hs[cur][byte]));
          float rg = fast_sigmoid(aR[cf][reg] + bRr[cf]);
          float zg = fast_sigmoid(aZ[cf][reg] + bZr[cf]);
          float ng = fast_tanh(aI[cf][reg] + bIr[cf] + rg * (aHn[cf][reg] + bHr[cf]));
          float h2 = (1.f - zg) * ng + zg * hold;
          txtacc[mf][cf][reg] += h2;
          *reinterpret_cast<unsigned short*>(&hs[cur ^ 1][byte]) = f32_to_bf16(h2);
        }
      }
    }
    cur ^= 1;
  }

#pragma unroll
  for (int mf = 0; mf < 4; ++mf)
#pragma unroll
    for (int cf = 0; cf < 2; ++cf) {
      const int j = wid * 32 + cf * 16 + l16;
#pragma unroll
      for (int reg = 0; reg < 4; ++reg) {
        const int row = mf * 16 + lk * 4 + reg;
        const int n = n0 + row;
        if (n < NN) txt[(size_t)n * HH + j] = f32_to_bf16(txtacc[mf][cf][reg]);
      }
    }
}

// ---------------- fused edge heads: LDS-free, barrier-free MFMA ----------------
// Block = 128 edges, 4 waves; wave = 32 edges x 128 cols x 2 heads.
// A-fragments gathered DIRECTLY from bf16 tables Tall[3][NN][256]
// (cols 0..127 = src-part, 128..255 = dst-part incl. bias), combined in-register.
__global__ __launch_bounds__(256, 2) void edge_mfma_k(
    const int* __restrict__ eidx,
    const unsigned short* __restrict__ Tall,
    const unsigned short* __restrict__ rw1T, const float* __restrict__ rb1,
    const float* __restrict__ rw2, const float* __restrict__ rb2,
    const unsigned short* __restrict__ cw1T, const float* __restrict__ cb1,
    const float* __restrict__ cw2, const float* __restrict__ cb2,
    float* __restrict__ out)
{
  const int tid = threadIdx.x;
  const int e0 = blockIdx.x * 128;
  const int wid = tid >> 6, lane = tid & 63;
  const int l16 = lane & 15, lk = lane >> 4;
  const int wr = wid * 32;

  int sidx[2], didx[2];
#pragma unroll
  for (int mf = 0; mf < 2; ++mf) {
    int e = e0 + wr + mf * 16 + l16;
    sidx[mf] = eidx[e];
    didx[mf] = eidx[NE + e];
  }

  f32x4 acc[2][2][8]; // [head][mf][nf]
#pragma unroll
  for (int h = 0; h < 2; ++h)
#pragma unroll
    for (int mf = 0; mf < 2; ++mf)
#pragma unroll
      for (int nf = 0; nf < 8; ++nf) acc[h][mf][nf] = f32x4{0.f, 0.f, 0.f, 0.f};

#pragma unroll
  for (int c = 0; c < 6; ++c) {
    const size_t tbase = (size_t)(c >> 1) * ((size_t)NN * 256) + (c & 1) * 64 + lk * 8;
    unsigned int af[2][2][4]; // [mf][ks][4 packed bf16 pairs]
#pragma unroll
    for (int mf = 0; mf < 2; ++mf) {
      const unsigned short* ps = Tall + tbase + (size_t)sidx[mf] * 256;
      const unsigned short* pd = Tall + tbase + (size_t)didx[mf] * 256 + 128;
#pragma unroll
      for (int ks = 0; ks < 2; ++ks) {
        uint4 us = *reinterpret_cast<const uint4*>(ps + ks * 32);
        uint4 ud = *reinterpret_cast<const uint4*>(pd + ks * 32);
        af[mf][ks][0] = combine2(us.x, ud.x);
        af[mf][ks][1] = combine2(us.y, ud.y);
        af[mf][ks][2] = combine2(us.z, ud.z);
        af[mf][ks][3] = combine2(us.w, ud.w);
      }
    }
#pragma unroll
    for (int ks = 0; ks < 2; ++ks) {
      short8v a0 = *reinterpret_cast<short8v*>(af[0][ks]);
      short8v a1 = *reinterpret_cast<short8v*>(af[1][ks]);
      int kglob = c * 64 + ks * 32 + lk * 8;
#pragma unroll
      for (int h = 0; h < 2; ++h) {
        const unsigned short* w1T = h ? cw1T : rw1T;
#pragma unroll
        for (int nf = 0; nf < 8; ++nf) {
          int col = nf * 16 + l16;
          short8v b = *reinterpret_cast<const short8v*>(&w1T[(size_t)col * 384 + kglob]);
          acc[h][0][nf] = MFMA_BF16(a0, b, acc[h][0][nf]);
          acc[h][1][nf] = MFMA_BF16(a1, b, acc[h][1][nf]);
        }
      }
    }
  }

#pragma unroll
  for (int h = 0; h < 2; ++h) {
    const float* b1 = h ? cb1 : rb1;
    const float* w2 = h ? cw2 : rw2;
    const float* b2 = h ? cb2 : rb2;
#pragma unroll
    for (int mf = 0; mf < 2; ++mf) {
#pragma unroll
      for (int reg = 0; reg < 4; ++reg) {
        float p0 = 0.f, p1 = 0.f;
#pragma unroll
        for (int nf = 0; nf < 8; ++nf) {
          int col = nf * 16 + l16;
          float hv = fmaxf(acc[h][mf][nf][reg] + b1[col], 0.f);
          p0 += hv * w2[col * 2];
          p1 += hv * w2[col * 2 + 1];
        }
#pragma unroll
        for (int m = 1; m < 16; m <<= 1) {
          p0 += __shfl_xor(p0, m);
          p1 += __shfl_xor(p1, m);
        }
        if (l16 == 0) {
          float l0 = p0 + b2[0], l1 = p1 + b2[1];
          float mx = fmaxf(l0, l1);
          float lse = mx + __logf(__expf(l0 - mx) + __expf(l1 - mx));
          int edge = e0 + wr + mf * 16 + lk * 4 + reg;
          float2 o2 = make_float2(l0 - lse, l1 - lse);
          *reinterpret_cast<float2*>(&out[(size_t)h * 2 * NE + (size_t)edge * 2]) = o2;
        }
      }
    }
  }
}

// ---------------- launch ----------------
extern "C" void kernel_launch(void* const* d_in, const int* in_sizes, int n_in,
                              void* d_out, int out_size, void* d_ws, size_t ws_size,
                              hipStream_t stream)
{
  const float* x       = (const float*)d_in[0];
  const int*   eidx    = (const int*)  d_in[1];
  const int*   xtext   = (const int*)  d_in[2];
  const float* imgf    = (const float*)d_in[3];
  const float* conv1_w = (const float*)d_in[4];
  const float* conv1_b = (const float*)d_in[5];
  const float* conv2_w = (const float*)d_in[6];
  const float* conv2_b = (const float*)d_in[7];
  const float* embed   = (const float*)d_in[8];
  const float* gwih    = (const float*)d_in[9];
  const float* gwhh    = (const float*)d_in[10];
  const float* gbih    = (const float*)d_in[11];
  const float* gbhh    = (const float*)d_in[12];
  const float* lpw     = (const float*)d_in[13];
  const float* lpb     = (const float*)d_in[14];
  const float* ltw     = (const float*)d_in[15];
  const float* ltb     = (const float*)d_in[16];
  const float* liw     = (const float*)d_in[17];
  const float* lib     = (const float*)d_in[18];
  const float* rw1     = (const float*)d_in[19];
  const float* rb1     = (const float*)d_in[20];
  const float* rw2     = (const float*)d_in[21];
  const float* rb2     = (const float*)d_in[22];
  const float* cw1     = (const float*)d_in[23];
  const float* cb1     = (const float*)d_in[24];
  const float* cw2     = (const float*)d_in[25];
  const float* cb2     = (const float*)d_in[26];
  float* out = (float*)d_out;

  char* w8 = (char*)d_ws;
  size_t off = 0;
  auto balloc = [&](size_t bytes) { void* p = w8 + off; off = (off + bytes + 255) & ~(size_t)255; return p; };
  float*          xw    = (float*)balloc((size_t)NN * HH * 4);
  float*          agg   = (float*)balloc((size_t)NN * HH * 4);
  float*          dinv  = (float*)balloc(NN * 4);
  unsigned short* nodeB = (unsigned short*)balloc((size_t)NN * HH * 2);   // h1 then pos
  unsigned short* txtB  = (unsigned short*)balloc((size_t)NN * HH * 2);
  unsigned short* imgB  = (unsigned short*)balloc((size_t)NN * 256 * 2);
  unsigned short* Tall  = (unsigned short*)balloc((size_t)3 * NN * 256 * 2);
  unsigned short* wihB  = (unsigned short*)balloc(384 * 64 * 2);
  unsigned short* whhB  = (unsigned short*)balloc(384 * 128 * 2);
  unsigned short* rw1T  = (unsigned short*)balloc(384 * 128 * 2);
  unsigned short* cw1T  = (unsigned short*)balloc(384 * 128 * 2);
  unsigned short* conv2T= (unsigned short*)balloc(128 * 128 * 2);
  unsigned short* TposW = (unsigned short*)balloc(256 * 128 * 2);
  unsigned short* TtxtW = (unsigned short*)balloc(256 * 128 * 2);
  unsigned short* TimgW = (unsigned short*)balloc(256 * 256 * 2);
  float*          bcomb = (float*)balloc(768 * 4);
  float*          brz   = (float*)balloc(256 * 4);
  float*          binv  = (float*)balloc(128 * 4);
  float*          bhnv  = (float*)balloc(128 * 4);

  dim3 b256(256);
  auto cdiv = [](int a, int b) { return (a + b - 1) / b; };
  const int MB = cdiv(NN, 128); // 157

  // ---- weight prep ----
  cvt_bf16_k<<<cdiv(384 * 64, 256), b256, 0, stream>>>(gwih, wihB, 384 * 64);
  cvt_bf16_k<<<cdiv(384 * 128, 256), b256, 0, stream>>>(gwhh, whhB, 384 * 128);
  transpose_bf16_k<<<cdiv(384 * 128, 256), b256, 0, stream>>>(rw1, rw1T, 384, 128);
  transpose_bf16_k<<<cdiv(384 * 128, 256), b256, 0, stream>>>(cw1, cw1T, 384, 128);
  transpose_bf16_k<<<cdiv(128 * 128, 256), b256, 0, stream>>>(conv2_w, conv2T, 128, 128);
  pack_tblw_k<<<cdiv(256 * 128, 256), b256, 0, stream>>>(lpw, TposW, 128);
  pack_tblw_k<<<cdiv(256 * 128, 256), b256, 0, stream>>>(ltw, TtxtW, 128);
  pack_tblw_k<<<cdiv(256 * 256, 256), b256, 0, stream>>>(liw, TimgW, 256);
  pack_bias_k<<<3, b256, 0, stream>>>(lpb, ltb, lib, bcomb);
  gru_bias_k<<<2, b256, 0, stream>>>(gbih, gbhh, brz, binv, bhnv);
  cvt_bf16_k<<<cdiv(NN * 256, 256), b256, 0, stream>>>(imgf, imgB, NN * 256);

  // ---- degree -> dinv ----
  fill_zero_k<<<cdiv(NN, 256), b256, 0, stream>>>(dinv, NN);
  deg_k<<<cdiv(NE, 256), b256, 0, stream>>>(eidx, dinv);
  dinv_k<<<cdiv(NN, 256), b256, 0, stream>>>(dinv);

  // ---- GCN layer 1 (f32 gemm for K=8) ----
  gemm_k<false, false, false><<<dim3(1, MB), b256, 0, stream>>>(x, conv1_w, nullptr, xw, NN, 128, 8, 8, 128, 128);
  fill_zero_k<<<cdiv(NN * HH, 256), b256, 0, stream>>>(agg, NN * HH);
  gcn_agg_k<<<NE / 4, b256, 0, stream>>>(eidx, xw, dinv, agg);
  gcn_fin_k<<<cdiv(NN * HH, 256), b256, 0, stream>>>(agg, xw, dinv, conv1_b, nodeB); // h1 bf16

  // ---- GCN layer 2 (MFMA) ----
  gemm_mfma_k<128, 128, false, false><<<dim3(MB, 1), b256, 0, stream>>>(nodeB, conv2T, nullptr, xw, NN);
  fill_zero_k<<<cdiv(NN * HH, 256), b256, 0, stream>>>(agg, NN * HH);
  gcn_agg_k<<<NE / 4, b256, 0, stream>>>(eidx, xw, dinv, agg);
  gcn_fin_k<<<cdiv(NN * HH, 256), b256, 0, stream>>>(agg, xw, dinv, conv2_b, nodeB); // pos bf16

  // ---- GRU -> txt bf16 ----
  gru_fused_k<<<cdiv(NN, 64), b256, 0, stream>>>(xtext, embed, wihB, whhB, brz, binv, bhnv, txtB);

  // ---- node tables (bf16, combined src|dst cols) ----
  gemm_mfma_k<128, 256, true, true><<<dim3(MB, 2), b256, 0, stream>>>(nodeB, TposW, bcomb,       Tall,                        NN);
  gemm_mfma_k<128, 256, true, true><<<dim3(MB, 2), b256, 0, stream>>>(txtB,  TtxtW, bcomb + 256, Tall + (size_t)NN * 256,     NN);
  gemm_mfma_k<256, 256, true, true><<<dim3(MB, 2), b256, 0, stream>>>(imgB,  TimgW, bcomb + 512, Tall + (size_t)2 * NN * 256, NN);

  // ---- fused edge heads + log_softmax ----
  edge_mfma_k<<<NE / 128, b256, 0, stream>>>(eidx, Tall, rw1T, rb1, rw2, rb2,
                                             cw1T, cb1, cw2, cb2, out);
}

// Round 5
// 923.942 us; speedup vs baseline: 5.1072x; 1.1205x over previous
//
#include <hip/hip_runtime.h>
#include <hip/hip_bf16.h>

#define NN 20000
#define NE 320000
#define LL 16
#define TT 64
#define HH 128

typedef __attribute__((ext_vector_type(8))) short short8v;
typedef __attribute__((ext_vector_type(4))) float f32x4;
#define MFMA_BF16(a,b,c) __builtin_amdgcn_mfma_f32_16x16x32_bf16(a,b,c,0,0,0)

__device__ inline unsigned short f32_to_bf16(float v) {
  unsigned int b = __float_as_uint(v);
  b += 0x7fffu + ((b >> 16) & 1u);
  return (unsigned short)(b >> 16);
}
__device__ inline float bf16_to_f32(unsigned short u) {
  return __uint_as_float(((unsigned int)u) << 16);
}
__device__ inline float fast_sigmoid(float x) {
  return __builtin_amdgcn_rcpf(1.f + __expf(-x));
}
__device__ inline float fast_tanh(float x) {
  float e = __expf(2.f * x);
  return 1.f - 2.f * __builtin_amdgcn_rcpf(e + 1.f);
}
__device__ inline unsigned int cvt_pk_bf16(float lo, float hi) {
  unsigned int r;
  asm("v_cvt_pk_bf16_f32 %0, %1, %2" : "=v"(r) : "v"(lo), "v"(hi));
  return r;
}
__device__ inline unsigned int combine2(unsigned int us, unsigned int ud) {
  float sl = __uint_as_float(us << 16);
  float sh = __uint_as_float(us & 0xffff0000u);
  float dl = __uint_as_float(ud << 16);
  float dh = __uint_as_float(ud & 0xffff0000u);
  return cvt_pk_bf16(fmaxf(sl + dl, 0.f), fmaxf(sh + dh, 0.f));
}

// ---------------- small utility kernels ----------------
__global__ void fill_zero_k(float* __restrict__ p, int n) {
  int i = blockIdx.x * 256 + threadIdx.x;
  if (i < n) p[i] = 0.f;
}

__global__ void histo_k(const int* __restrict__ eidx, int* __restrict__ ideg) {
  int e = blockIdx.x * 256 + threadIdx.x;
  if (e < NE) atomicAdd(&ideg[eidx[NE + e]], 1);
}

// single-block exclusive scan over NN entries -> rowptr[0..NN]
__global__ void scan_k(const int* __restrict__ ideg, int* __restrict__ rowptr) {
  __shared__ int sh[256];
  __shared__ int carry;
  const int tid = threadIdx.x;
  if (tid == 0) carry = 0;
  __syncthreads();
  for (int base = 0; base < NN; base += 256) {
    int v = (base + tid < NN) ? ideg[base + tid] : 0;
    sh[tid] = v;
    __syncthreads();
#pragma unroll
    for (int off = 1; off < 256; off <<= 1) {
      int t = (tid >= off) ? sh[tid - off] : 0;
      __syncthreads();
      sh[tid] += t;
      __syncthreads();
    }
    if (base + tid < NN) rowptr[base + tid] = carry + sh[tid] - v;
    __syncthreads();
    if (tid == 255) carry += sh[255];
    __syncthreads();
  }
  if (tid == 0) rowptr[NN] = carry;
}

__global__ void dinv_csr_k(const int* __restrict__ rowptr, float* __restrict__ dinv) {
  int i = blockIdx.x * 256 + threadIdx.x;
  if (i < NN) dinv[i] = rsqrtf((float)(rowptr[i + 1] - rowptr[i]) + 1.f);
}

__global__ void scatter_k(const int* __restrict__ eidx, int* __restrict__ cursor,
                          int* __restrict__ esrc_s, int* __restrict__ edst_s,
                          int* __restrict__ eorig_s) {
  int e = blockIdx.x * 256 + threadIdx.x;
  if (e >= NE) return;
  int s = eidx[e], d = eidx[NE + e];
  int pos = atomicAdd(&cursor[d], 1);
  esrc_s[pos] = s;
  edst_s[pos] = d;
  eorig_s[pos] = e;
}

// atomic-free GCN aggregate + self-loop + bias + relu -> bf16. One wave per dst node.
__global__ __launch_bounds__(256) void gcn_csr_k(
    const int* __restrict__ rowptr, const int* __restrict__ esrc_s,
    const float* __restrict__ xw, const float* __restrict__ dinv,
    const float* __restrict__ bias, unsigned short* __restrict__ outB)
{
  int node = blockIdx.x * 4 + (threadIdx.x >> 6);
  int lane = threadIdx.x & 63;
  if (node >= NN) return;
  float dd = dinv[node];
  int beg = rowptr[node], end = rowptr[node + 1];
  float a0 = 0.f, a1 = 0.f;
  for (int i = beg; i < end; ++i) {
    int s = esrc_s[i];
    float nrm = dinv[s] * dd;
    a0 += xw[(size_t)s * HH + lane] * nrm;
    a1 += xw[(size_t)s * HH + 64 + lane] * nrm;
  }
  a0 += xw[(size_t)node * HH + lane] * dd * dd;
  a1 += xw[(size_t)node * HH + 64 + lane] * dd * dd;
  outB[(size_t)node * HH + lane]      = f32_to_bf16(fmaxf(a0 + bias[lane], 0.f));
  outB[(size_t)node * HH + 64 + lane] = f32_to_bf16(fmaxf(a1 + bias[64 + lane], 0.f));
}

__global__ void cvt_bf16_k(const float* __restrict__ in, unsigned short* __restrict__ out, int n) {
  int i = blockIdx.x * 256 + threadIdx.x;
  if (i < n) out[i] = f32_to_bf16(in[i]);
}

__global__ void transpose_bf16_k(const float* __restrict__ in, unsigned short* __restrict__ out,
                                 int R, int C) {
  int i = blockIdx.x * 256 + threadIdx.x;
  if (i >= R * C) return;
  int c = i / R, r = i - c * R;
  out[i] = f32_to_bf16(in[r * C + c]);
}

__global__ void gru_bias_k(const float* __restrict__ bih, const float* __restrict__ bhh,
                           float* __restrict__ brz, float* __restrict__ binv, float* __restrict__ bhnv) {
  int i = blockIdx.x * 256 + threadIdx.x;
  if (i < 256) brz[i] = bih[i] + bhh[i];
  else if (i < 384) binv[i - 256] = bih[i];
  else if (i < 512) bhnv[i - 384] = bhh[i - 128];
}

__global__ void pack_tblw_k(const float* __restrict__ w, unsigned short* __restrict__ wt, int K) {
  int i = blockIdx.x * 256 + threadIdx.x;
  if (i >= 256 * K) return;
  int col = i / K, k = i - col * K;
  float v = (col < 128) ? w[k * 128 + col] : w[(K + k) * 128 + (col - 128)];
  wt[i] = f32_to_bf16(v);
}

__global__ void pack_bias_k(const float* __restrict__ bp, const float* __restrict__ bt,
                            const float* __restrict__ bi, float* __restrict__ bc) {
  int i = blockIdx.x * 256 + threadIdx.x;
  if (i >= 768) return;
  int t = i >> 8, j = i & 255;
  const float* b = t == 0 ? bp : t == 1 ? bt : bi;
  bc[i] = (j < 128) ? 0.f : b[j - 128];
}

// ---------------- generic tiled f32 GEMM (conv1 only, K=8) ----
template<bool TRANSB, bool ADD_BIAS, bool RELU>
__global__ __launch_bounds__(256) void gemm_k(
    const float* __restrict__ A, const float* __restrict__ B,
    const float* __restrict__ bias, float* __restrict__ C,
    int M, int N, int K, int lda, int ldb, int ldc)
{
  __shared__ float As[16][132];
  __shared__ float Bs[16][132];
  int tid = threadIdx.x;
  int bm = blockIdx.y * 128, bn = blockIdx.x * 128;
  int tx = tid & 15, ty = tid >> 4;
  float acc[8][8];
#pragma unroll
  for (int i = 0; i < 8; ++i)
#pragma unroll
    for (int j = 0; j < 8; ++j) acc[i][j] = 0.f;

  for (int k0 = 0; k0 < K; k0 += 16) {
#pragma unroll
    for (int l = 0; l < 2; ++l) {
      int s = tid + l * 256;
      int r = s >> 2, kq = s & 3;
      int gr = bm + r, gk = k0 + kq * 4;
      float4 v = make_float4(0.f, 0.f, 0.f, 0.f);
      if (gr < M && gk < K)
        v = *reinterpret_cast<const float4*>(&A[(size_t)gr * lda + gk]);
      As[kq * 4 + 0][r] = v.x; As[kq * 4 + 1][r] = v.y;
      As[kq * 4 + 2][r] = v.z; As[kq * 4 + 3][r] = v.w;
    }
#pragma unroll
    for (int l = 0; l < 8; ++l) {
      int s = tid + l * 256;
      int kk = s >> 7, c = s & 127;
      int gk = k0 + kk, gc = bn + c;
      Bs[kk][c] = (gk < K && gc < N) ? B[(size_t)gk * ldb + gc] : 0.f;
    }
    __syncthreads();
#pragma unroll
    for (int kk = 0; kk < 16; ++kk) {
      float4 a0 = *reinterpret_cast<const float4*>(&As[kk][ty * 8]);
      float4 a1 = *reinterpret_cast<const float4*>(&As[kk][ty * 8 + 4]);
      float4 b0 = *reinterpret_cast<const float4*>(&Bs[kk][tx * 8]);
      float4 b1 = *reinterpret_cast<const float4*>(&Bs[kk][tx * 8 + 4]);
      float av[8] = {a0.x, a0.y, a0.z, a0.w, a1.x, a1.y, a1.z, a1.w};
      float bv[8] = {b0.x, b0.y, b0.z, b0.w, b1.x, b1.y, b1.z, b1.w};
#pragma unroll
      for (int i = 0; i < 8; ++i)
#pragma unroll
        for (int j = 0; j < 8; ++j)
          acc[i][j] += av[i] * bv[j];
    }
    __syncthreads();
  }
#pragma unroll
  for (int i = 0; i < 8; ++i) {
    int gr = bm + ty * 8 + i;
    if (gr >= M) continue;
#pragma unroll
    for (int j = 0; j < 8; ++j) {
      int gc = bn + tx * 8 + j;
      if (gc >= N) continue;
      float v = acc[i][j];
      if (ADD_BIAS) v += bias[gc];
      if (RELU) v = fmaxf(v, 0.f);
      C[(size_t)gr * ldc + gc] = v;
    }
  }
}

// ---------------- direct-fragment MFMA GEMM (bf16 A, bf16 WT[col][K]) --------
template<int KDIM, int NCOLS, bool OUTBF16, bool ADDBIAS>
__global__ __launch_bounds__(256) void gemm_mfma_k(
    const unsigned short* __restrict__ A, const unsigned short* __restrict__ WT,
    const float* __restrict__ bias, void* __restrict__ Cv, int M)
{
  const int tid = threadIdx.x;
  const int wid = tid >> 6, lane = tid & 63;
  const int l16 = lane & 15, lk = lane >> 4;
  const int bm = blockIdx.x * 128, bn = blockIdx.y * 128;
  const int wr = wid * 32;

  int row[2];
#pragma unroll
  for (int mf = 0; mf < 2; ++mf) {
    int r = bm + wr + mf * 16 + l16;
    row[mf] = r < M ? r : M - 1;
  }
  f32x4 acc[2][8];
#pragma unroll
  for (int mf = 0; mf < 2; ++mf)
#pragma unroll
    for (int nf = 0; nf < 8; ++nf) acc[mf][nf] = f32x4{0.f, 0.f, 0.f, 0.f};

#pragma unroll
  for (int kc = 0; kc < KDIM / 32; ++kc) {
    short8v a[2];
#pragma unroll
    for (int mf = 0; mf < 2; ++mf)
      a[mf] = *reinterpret_cast<const short8v*>(&A[(size_t)row[mf] * KDIM + kc * 32 + lk * 8]);
#pragma unroll
    for (int nf = 0; nf < 8; ++nf) {
      int col = bn + nf * 16 + l16;
      short8v b = *reinterpret_cast<const short8v*>(&WT[(size_t)col * KDIM + kc * 32 + lk * 8]);
      acc[0][nf] = MFMA_BF16(a[0], b, acc[0][nf]);
      acc[1][nf] = MFMA_BF16(a[1], b, acc[1][nf]);
    }
  }
#pragma unroll
  for (int mf = 0; mf < 2; ++mf)
#pragma unroll
    for (int nf = 0; nf < 8; ++nf) {
      int col = bn + nf * 16 + l16;
      float bb = ADDBIAS ? bias[col] : 0.f;
#pragma unroll
      for (int reg = 0; reg < 4; ++reg) {
        int r = bm + wr + mf * 16 + lk * 4 + reg;
        if (r < M) {
          float v = acc[mf][nf][reg] + bb;
          if (OUTBF16) ((unsigned short*)Cv)[(size_t)r * NCOLS + col] = f32_to_bf16(v);
          else         ((float*)Cv)[(size_t)r * NCOLS + col] = v;
        }
      }
    }
}

// ---------------- fused persistent GRU (weights in registers) --------
__global__ __launch_bounds__(256, 1) void gru_fused_k(
    const int* __restrict__ xtext, const float* __restrict__ embed,
    const unsigned short* __restrict__ wihB, const unsigned short* __restrict__ whhB,
    const float* __restrict__ brz, const float* __restrict__ binv, const float* __restrict__ bhnv,
    unsigned short* __restrict__ txt)
{
  __shared__ unsigned char hs[2][64 * 256];
  __shared__ unsigned char xs[64 * 128];
  const int tid = threadIdx.x;
  const int n0 = blockIdx.x * 64;
  const int wid = tid >> 6, lane = tid & 63;
  const int l16 = lane & 15, lk = lane >> 4;

  for (int i = tid; i < 64 * 256 / 4; i += 256) ((unsigned int*)hs[0])[i] = 0u;

  short8v wR[2][2], wZ[2][2], wN[2][2];
  short8v uR[2][4], uZ[2][4], uN[2][4];
  float bRr[2], bZr[2], bIr[2], bHr[2];
#pragma unroll
  for (int cf = 0; cf < 2; ++cf) {
    int col = wid * 32 + cf * 16 + l16;
#pragma unroll
    for (int ks = 0; ks < 2; ++ks) {
      wR[cf][ks] = *reinterpret_cast<const short8v*>(&wihB[(col      ) * 64 + ks * 32 + lk * 8]);
      wZ[cf][ks] = *reinterpret_cast<const short8v*>(&wihB[(col + 128) * 64 + ks * 32 + lk * 8]);
      wN[cf][ks] = *reinterpret_cast<const short8v*>(&wihB[(col + 256) * 64 + ks * 32 + lk * 8]);
    }
#pragma unroll
    for (int ks = 0; ks < 4; ++ks) {
      uR[cf][ks] = *reinterpret_cast<const short8v*>(&whhB[(col      ) * 128 + ks * 32 + lk * 8]);
      uZ[cf][ks] = *reinterpret_cast<const short8v*>(&whhB[(col + 128) * 128 + ks * 32 + lk * 8]);
      uN[cf][ks] = *reinterpret_cast<const short8v*>(&whhB[(col + 256) * 128 + ks * 32 + lk * 8]);
    }
    bRr[cf] = brz[col]; bZr[cf] = brz[128 + col];
    bIr[cf] = binv[col]; bHr[cf] = bhnv[col];
  }

  f32x4 txtacc[4][2];
#pragma unroll
  for (int mf = 0; mf < 4; ++mf)
#pragma unroll
    for (int cf = 0; cf < 2; ++cf) txtacc[mf][cf] = f32x4{0.f, 0.f, 0.f, 0.f};

  int cur = 0;
  for (int t = 0; t < LL; ++t) {
    __syncthreads();
    {
      const int k4 = tid & 15, r0 = tid >> 4;
#pragma unroll
      for (int rep = 0; rep < 4; ++rep) {
        int row = r0 + rep * 16;
        int n = n0 + row; if (n >= NN) n = NN - 1;
        int tok = xtext[n * LL + t];
        float4 v = *reinterpret_cast<const float4*>(&embed[(size_t)tok * TT + k4 * 4]);
        ushort4 w;
        w.x = f32_to_bf16(v.x); w.y = f32_to_bf16(v.y);
        w.z = f32_to_bf16(v.z); w.w = f32_to_bf16(v.w);
        *reinterpret_cast<ushort4*>(&xs[row * 128 + ((k4 * 8) ^ ((row & 7) << 4))]) = w;
      }
    }
    __syncthreads();

#pragma unroll
    for (int mf = 0; mf < 4; ++mf) {
      const int arow = mf * 16 + l16;
      const int asw = (arow & 7) << 4;
      short8v ax[2], ah[4];
#pragma unroll
      for (int ks = 0; ks < 2; ++ks)
        ax[ks] = *reinterpret_cast<const short8v*>(&xs[arow * 128 + ((ks * 64 + lk * 16) ^ asw)]);
#pragma unroll
      for (int ks = 0; ks < 4; ++ks)
        ah[ks] = *reinterpret_cast<const short8v*>(&hs[cur][arow * 256 + ((ks * 64 + lk * 16) ^ asw)]);

      f32x4 aR[2], aZ[2], aI[2], aHn[2];
#pragma unroll
      for (int cf = 0; cf < 2; ++cf) {
        aR[cf] = f32x4{0.f, 0.f, 0.f, 0.f}; aZ[cf] = f32x4{0.f, 0.f, 0.f, 0.f};
        aI[cf] = f32x4{0.f, 0.f, 0.f, 0.f}; aHn[cf] = f32x4{0.f, 0.f, 0.f, 0.f};
#pragma unroll
        for (int ks = 0; ks < 2; ++ks) {
          aR[cf] = MFMA_BF16(ax[ks], wR[cf][ks], aR[cf]);
          aZ[cf] = MFMA_BF16(ax[ks], wZ[cf][ks], aZ[cf]);
          aI[cf] = MFMA_BF16(ax[ks], wN[cf][ks], aI[cf]);
        }
#pragma unroll
        for (int ks = 0; ks < 4; ++ks) {
          aR[cf]  = MFMA_BF16(ah[ks], uR[cf][ks], aR[cf]);
          aZ[cf]  = MFMA_BF16(ah[ks], uZ[cf][ks], aZ[cf]);
          aHn[cf] = MFMA_BF16(ah[ks], uN[cf][ks], aHn[cf]);
        }
      }

#pragma unroll
      for (int cf = 0; cf < 2; ++cf) {
        const int j = wid * 32 + cf * 16 + l16;
#pragma unroll
        for (int reg = 0; reg < 4; ++reg) {
          const int row = mf * 16 + lk * 4 + reg;
          const int byte = row * 256 + ((j * 2) ^ ((row & 7) << 4));
          float hold = bf16_to_f32(*reinterpret_cast<unsigned short*>(&hs[cur][byte]));
          float rg = fast_sigmoid(aR[cf][reg] + bRr[cf]);
          float zg = fast_sigmoid(aZ[cf][reg] + bZr[cf]);
          float ng = fast_tanh(aI[cf][reg] + bIr[cf] + rg * (aHn[cf][reg] + bHr[cf]));
          float h2 = (1.f - zg) * ng + zg * hold;
          txtacc[mf][cf][reg] += h2;
          *reinterpret_cast<unsigned short*>(&hs[cur ^ 1][byte]) = f32_to_bf16(h2);
        }
      }
    }
    cur ^= 1;
  }

#pragma unroll
  for (int mf = 0; mf < 4; ++mf)
#pragma unroll
    for (int cf = 0; cf < 2; ++cf) {
      const int j = wid * 32 + cf * 16 + l16;
#pragma unroll
      for (int reg = 0; reg < 4; ++reg) {
        const int row = mf * 16 + lk * 4 + reg;
        const int n = n0 + row;
        if (n < NN) txt[(size_t)n * HH + j] = f32_to_bf16(txtacc[mf][cf][reg]);
      }
    }
}

// ---------------- fused edge heads: LDS-free, dst-sorted, depth-2 prefetch ----
__global__ __launch_bounds__(256, 2) void edge_mfma_k(
    const int* __restrict__ esrc_s, const int* __restrict__ edst_s,
    const int* __restrict__ eorig_s,
    const unsigned short* __restrict__ Tall,
    const unsigned short* __restrict__ rw1T, const float* __restrict__ rb1,
    const float* __restrict__ rw2, const float* __restrict__ rb2,
    const unsigned short* __restrict__ cw1T, const float* __restrict__ cb1,
    const float* __restrict__ cw2, const float* __restrict__ cb2,
    float* __restrict__ out)
{
  const int tid = threadIdx.x;
  const int e0 = blockIdx.x * 128;
  const int wid = tid >> 6, lane = tid & 63;
  const int l16 = lane & 15, lk = lane >> 4;
  const int wr = wid * 32;
  const int lkoff = lk * 8;

  size_t soff[2], doff[2];
#pragma unroll
  for (int mf = 0; mf < 2; ++mf) {
    int e = e0 + wr + mf * 16 + l16;
    soff[mf] = (size_t)esrc_s[e] * 256;
    doff[mf] = (size_t)edst_s[e] * 256 + 128;
  }

  f32x4 acc[2][2][8]; // [head][mf][nf]
#pragma unroll
  for (int h = 0; h < 2; ++h)
#pragma unroll
    for (int mf = 0; mf < 2; ++mf)
#pragma unroll
      for (int nf = 0; nf < 8; ++nf) acc[h][mf][nf] = f32x4{0.f, 0.f, 0.f, 0.f};

  uint4 ra[2][2], rd_[2][2], na[2][2], nd_[2][2];

#define LOADC(c, RS, RD) { \
  const unsigned short* tb = Tall + (size_t)((c) >> 1) * ((size_t)NN * 256) + ((c) & 1) * 64 + lkoff; \
  _Pragma("unroll") \
  for (int mf = 0; mf < 2; ++mf) { \
    RS[mf][0] = *reinterpret_cast<const uint4*>(tb + soff[mf]); \
    RS[mf][1] = *reinterpret_cast<const uint4*>(tb + soff[mf] + 32); \
    RD[mf][0] = *reinterpret_cast<const uint4*>(tb + doff[mf]); \
    RD[mf][1] = *reinterpret_cast<const uint4*>(tb + doff[mf] + 32); \
  } }

#define PROC(c, RS, RD) { \
  _Pragma("unroll") \
  for (int ks = 0; ks < 2; ++ks) { \
    unsigned int af0[4], af1[4]; \
    af0[0] = combine2(RS[0][ks].x, RD[0][ks].x); \
    af0[1] = combine2(RS[0][ks].y, RD[0][ks].y); \
    af0[2] = combine2(RS[0][ks].z, RD[0][ks].z); \
    af0[3] = combine2(RS[0][ks].w, RD[0][ks].w); \
    af1[0] = combine2(RS[1][ks].x, RD[1][ks].x); \
    af1[1] = combine2(RS[1][ks].y, RD[1][ks].y); \
    af1[2] = combine2(RS[1][ks].z, RD[1][ks].z); \
    af1[3] = combine2(RS[1][ks].w, RD[1][ks].w); \
    short8v a0 = *reinterpret_cast<short8v*>(af0); \
    short8v a1 = *reinterpret_cast<short8v*>(af1); \
    int kglob = (c) * 64 + ks * 32 + lkoff; \
    _Pragma("unroll") \
    for (int nf = 0; nf < 8; ++nf) { \
      int col = nf * 16 + l16; \
      short8v br = *reinterpret_cast<const short8v*>(&rw1T[(size_t)col * 384 + kglob]); \
      acc[0][0][nf] = MFMA_BF16(a0, br, acc[0][0][nf]); \
      acc[0][1][nf] = MFMA_BF16(a1, br, acc[0][1][nf]); \
      short8v bc = *reinterpret_cast<const short8v*>(&cw1T[(size_t)col * 384 + kglob]); \
      acc[1][0][nf] = MFMA_BF16(a0, bc, acc[1][0][nf]); \
      acc[1][1][nf] = MFMA_BF16(a1, bc, acc[1][1][nf]); \
    } \
  } }

  LOADC(0, ra, rd_)
  LOADC(1, na, nd_)
  PROC(0, ra, rd_)
  LOADC(2, ra, rd_)
  PROC(1, na, nd_)
  LOADC(3, na, nd_)
  PROC(2, ra, rd_)
  LOADC(4, ra, rd_)
  PROC(3, na, nd_)
  LOADC(5, na, nd_)
  PROC(4, ra, rd_)
  PROC(5, na, nd_)
#undef LOADC
#undef PROC

#pragma unroll
  for (int h = 0; h < 2; ++h) {
    const float* b1 = h ? cb1 : rb1;
    const float* w2 = h ? cw2 : rw2;
    const float* b2 = h ? cb2 : rb2;
#pragma unroll
    for (int mf = 0; mf < 2; ++mf) {
#pragma unroll
      for (int reg = 0; reg < 4; ++reg) {
        float p0 = 0.f, p1 = 0.f;
#pragma unroll
        for (int nf = 0; nf < 8; ++nf) {
          int col = nf * 16 + l16;
          float hv = fmaxf(acc[h][mf][nf][reg] + b1[col], 0.f);
          p0 += hv * w2[col * 2];
          p1 += hv * w2[col * 2 + 1];
        }
#pragma unroll
        for (int m = 1; m < 16; m <<= 1) {
          p0 += __shfl_xor(p0, m);
          p1 += __shfl_xor(p1, m);
        }
        if (l16 == 0) {
          int orig = eorig_s[e0 + wr + mf * 16 + lk * 4 + reg];
          float l0 = p0 + b2[0], l1 = p1 + b2[1];
          float mx = fmaxf(l0, l1);
          float lse = mx + __logf(__expf(l0 - mx) + __expf(l1 - mx));
          float2 o2 = make_float2(l0 - lse, l1 - lse);
          *reinterpret_cast<float2*>(&out[(size_t)h * 2 * NE + (size_t)orig * 2]) = o2;
        }
      }
    }
  }
}

// ---------------- launch ----------------
extern "C" void kernel_launch(void* const* d_in, const int* in_sizes, int n_in,
                              void* d_out, int out_size, void* d_ws, size_t ws_size,
                              hipStream_t stream)
{
  const float* x       = (const float*)d_in[0];
  const int*   eidx    = (const int*)  d_in[1];
  const int*   xtext   = (const int*)  d_in[2];
  const float* imgf    = (const float*)d_in[3];
  const float* conv1_w = (const float*)d_in[4];
  const float* conv1_b = (const float*)d_in[5];
  const float* conv2_w = (const float*)d_in[6];
  const float* conv2_b = (const float*)d_in[7];
  const float* embed   = (const float*)d_in[8];
  const float* gwih    = (const float*)d_in[9];
  const float* gwhh    = (const float*)d_in[10];
  const float* gbih    = (const float*)d_in[11];
  const float* gbhh    = (const float*)d_in[12];
  const float* lpw     = (const float*)d_in[13];
  const float* lpb     = (const float*)d_in[14];
  const float* ltw     = (const float*)d_in[15];
  const float* ltb     = (const float*)d_in[16];
  const float* liw     = (const float*)d_in[17];
  const float* lib     = (const float*)d_in[18];
  const float* rw1     = (const float*)d_in[19];
  const float* rb1     = (const float*)d_in[20];
  const float* rw2     = (const float*)d_in[21];
  const float* rb2     = (const float*)d_in[22];
  const float* cw1     = (const float*)d_in[23];
  const float* cb1     = (const float*)d_in[24];
  const float* cw2     = (const float*)d_in[25];
  const float* cb2     = (const float*)d_in[26];
  float* out = (float*)d_out;

  char* w8 = (char*)d_ws;
  size_t off = 0;
  auto balloc = [&](size_t bytes) { void* p = w8 + off; off = (off + bytes + 255) & ~(size_t)255; return p; };
  float*          xw     = (float*)balloc((size_t)NN * HH * 4);
  float*          dinv   = (float*)balloc(NN * 4);
  int*            ideg   = (int*)balloc((NN + 1) * 4);
  int*            rowptr = (int*)balloc((NN + 1) * 4);
  int*            cursor = (int*)balloc((NN + 1) * 4);
  int*            esrc_s = (int*)balloc((size_t)NE * 4);
  int*            edst_s = (int*)balloc((size_t)NE * 4);
  int*            eorig_s= (int*)balloc((size_t)NE * 4);
  unsigned short* nodeB  = (unsigned short*)balloc((size_t)NN * HH * 2);
  unsigned short* txtB   = (unsigned short*)balloc((size_t)NN * HH * 2);
  unsigned short* imgB   = (unsigned short*)balloc((size_t)NN * 256 * 2);
  unsigned short* Tall   = (unsigned short*)balloc((size_t)3 * NN * 256 * 2);
  unsigned short* wihB   = (unsigned short*)balloc(384 * 64 * 2);
  unsigned short* whhB   = (unsigned short*)balloc(384 * 128 * 2);
  unsigned short* rw1T   = (unsigned short*)balloc(384 * 128 * 2);
  unsigned short* cw1T   = (unsigned short*)balloc(384 * 128 * 2);
  unsigned short* conv2T = (unsigned short*)balloc(128 * 128 * 2);
  unsigned short* TposW  = (unsigned short*)balloc(256 * 128 * 2);
  unsigned short* TtxtW  = (unsigned short*)balloc(256 * 128 * 2);
  unsigned short* TimgW  = (unsigned short*)balloc(256 * 256 * 2);
  float*          bcomb  = (float*)balloc(768 * 4);
  float*          brz    = (float*)balloc(256 * 4);
  float*          binv   = (float*)balloc(128 * 4);
  float*          bhnv   = (float*)balloc(128 * 4);

  dim3 b256(256);
  auto cdiv = [](int a, int b) { return (a + b - 1) / b; };
  const int MB = cdiv(NN, 128); // 157

  // ---- weight prep ----
  cvt_bf16_k<<<cdiv(384 * 64, 256), b256, 0, stream>>>(gwih, wihB, 384 * 64);
  cvt_bf16_k<<<cdiv(384 * 128, 256), b256, 0, stream>>>(gwhh, whhB, 384 * 128);
  transpose_bf16_k<<<cdiv(384 * 128, 256), b256, 0, stream>>>(rw1, rw1T, 384, 128);
  transpose_bf16_k<<<cdiv(384 * 128, 256), b256, 0, stream>>>(cw1, cw1T, 384, 128);
  transpose_bf16_k<<<cdiv(128 * 128, 256), b256, 0, stream>>>(conv2_w, conv2T, 128, 128);
  pack_tblw_k<<<cdiv(256 * 128, 256), b256, 0, stream>>>(lpw, TposW, 128);
  pack_tblw_k<<<cdiv(256 * 128, 256), b256, 0, stream>>>(ltw, TtxtW, 128);
  pack_tblw_k<<<cdiv(256 * 256, 256), b256, 0, stream>>>(liw, TimgW, 256);
  pack_bias_k<<<3, b256, 0, stream>>>(lpb, ltb, lib, bcomb);
  gru_bias_k<<<2, b256, 0, stream>>>(gbih, gbhh, brz, binv, bhnv);
  cvt_bf16_k<<<cdiv(NN * 256, 256), b256, 0, stream>>>(imgf, imgB, NN * 256);

  // ---- dst-sorted CSR ----
  fill_zero_k<<<cdiv(NN + 1, 256), b256, 0, stream>>>((float*)ideg, NN + 1);
  histo_k<<<cdiv(NE, 256), b256, 0, stream>>>(eidx, ideg);
  scan_k<<<1, b256, 0, stream>>>(ideg, rowptr);
  dinv_csr_k<<<cdiv(NN, 256), b256, 0, stream>>>(rowptr, dinv);
  hipMemcpyAsync(cursor, rowptr, (NN + 1) * sizeof(int), hipMemcpyDeviceToDevice, stream);
  scatter_k<<<cdiv(NE, 256), b256, 0, stream>>>(eidx, cursor, esrc_s, edst_s, eorig_s);

  // ---- GCN layer 1 (f32 gemm K=8 -> CSR aggregate) ----
  gemm_k<false, false, false><<<dim3(1, MB), b256, 0, stream>>>(x, conv1_w, nullptr, xw, NN, 128, 8, 8, 128, 128);
  gcn_csr_k<<<cdiv(NN, 4), b256, 0, stream>>>(rowptr, esrc_s, xw, dinv, conv1_b, nodeB); // h1 bf16

  // ---- GCN layer 2 (MFMA -> CSR aggregate) ----
  gemm_mfma_k<128, 128, false, false><<<dim3(MB, 1), b256, 0, stream>>>(nodeB, conv2T, nullptr, xw, NN);
  gcn_csr_k<<<cdiv(NN, 4), b256, 0, stream>>>(rowptr, esrc_s, xw, dinv, conv2_b, nodeB); // pos bf16

  // ---- GRU -> txt bf16 ----
  gru_fused_k<<<cdiv(NN, 64), b256, 0, stream>>>(xtext, embed, wihB, whhB, brz, binv, bhnv, txtB);

  // ---- node tables (bf16, combined src|dst cols) ----
  gemm_mfma_k<128, 256, true, true><<<dim3(MB, 2), b256, 0, stream>>>(nodeB, TposW, bcomb,       Tall,                        NN);
  gemm_mfma_k<128, 256, true, true><<<dim3(MB, 2), b256, 0, stream>>>(txtB,  TtxtW, bcomb + 256, Tall + (size_t)NN * 256,     NN);
  gemm_mfma_k<256, 256, true, true><<<dim3(MB, 2), b256, 0, stream>>>(imgB,  TimgW, bcomb + 512, Tall + (size_t)2 * NN * 256, NN);

  // ---- fused edge heads + log_softmax (dst-sorted order) ----
  edge_mfma_k<<<NE / 128, b256, 0, stream>>>(esrc_s, edst_s, eorig_s, Tall,
                                             rw1T, rb1, rw2, rb2, cw1T, cb1, cw2, cb2, out);
}

// Round 6
// 795.550 us; speedup vs baseline: 5.9314x; 1.1614x over previous
//
#include <hip/hip_runtime.h>
#include <hip/hip_bf16.h>

#define NN 20000
#define NE 320000
#define LL 16
#define TT 64
#define HH 128

typedef __attribute__((ext_vector_type(8))) short short8v;
typedef __attribute__((ext_vector_type(4))) float f32x4;
#define MFMA_BF16(a,b,c) __builtin_amdgcn_mfma_f32_16x16x32_bf16(a,b,c,0,0,0)

__device__ inline unsigned short f32_to_bf16(float v) {
  unsigned int b = __float_as_uint(v);
  b += 0x7fffu + ((b >> 16) & 1u);
  return (unsigned short)(b >> 16);
}
__device__ inline float bf16_to_f32(unsigned short u) {
  return __uint_as_float(((unsigned int)u) << 16);
}
__device__ inline float fast_sigmoid(float x) {
  return __builtin_amdgcn_rcpf(1.f + __expf(-x));
}
__device__ inline float fast_tanh(float x) {
  float e = __expf(2.f * x);
  return 1.f - 2.f * __builtin_amdgcn_rcpf(e + 1.f);
}
__device__ inline unsigned int cvt_pk_bf16(float lo, float hi) {
  unsigned int r;
  asm("v_cvt_pk_bf16_f32 %0, %1, %2" : "=v"(r) : "v"(lo), "v"(hi));
  return r;
}
__device__ inline unsigned int combine2(unsigned int us, unsigned int ud) {
  float sl = __uint_as_float(us << 16);
  float sh = __uint_as_float(us & 0xffff0000u);
  float dl = __uint_as_float(ud << 16);
  float dh = __uint_as_float(ud & 0xffff0000u);
  return cvt_pk_bf16(fmaxf(sl + dl, 0.f), fmaxf(sh + dh, 0.f));
}

// ---------------- fused prep: all weight conversions in one kernel ----------------
__global__ void prep_k(
    const float* __restrict__ gwih, const float* __restrict__ gwhh,
    const float* __restrict__ rw1, const float* __restrict__ cw1,
    const float* __restrict__ conv2w,
    const float* __restrict__ lpw, const float* __restrict__ ltw, const float* __restrict__ liw,
    const float* __restrict__ lpb, const float* __restrict__ ltb, const float* __restrict__ lib,
    const float* __restrict__ gbih, const float* __restrict__ gbhh,
    unsigned short* __restrict__ wihB, unsigned short* __restrict__ whhB,
    unsigned short* __restrict__ rw1T, unsigned short* __restrict__ cw1T,
    unsigned short* __restrict__ conv2T,
    unsigned short* __restrict__ TposW, unsigned short* __restrict__ TtxtW,
    unsigned short* __restrict__ TimgW,
    float* __restrict__ bcomb, float* __restrict__ brz,
    float* __restrict__ binv, float* __restrict__ bhnv)
{
  int i = blockIdx.x * 256 + threadIdx.x;
  if (i < 24576) { wihB[i] = f32_to_bf16(gwih[i]); return; } i -= 24576;
  if (i < 49152) { whhB[i] = f32_to_bf16(gwhh[i]); return; } i -= 49152;
  if (i < 49152) { int c = i / 384, r = i - c * 384; rw1T[i] = f32_to_bf16(rw1[r * 128 + c]); return; } i -= 49152;
  if (i < 49152) { int c = i / 384, r = i - c * 384; cw1T[i] = f32_to_bf16(cw1[r * 128 + c]); return; } i -= 49152;
  if (i < 16384) { int c = i / 128, r = i - c * 128; conv2T[i] = f32_to_bf16(conv2w[r * 128 + c]); return; } i -= 16384;
  if (i < 32768) { int col = i / 128, k = i - col * 128;
    float v = (col < 128) ? lpw[k * 128 + col] : lpw[(128 + k) * 128 + (col - 128)];
    TposW[i] = f32_to_bf16(v); return; } i -= 32768;
  if (i < 32768) { int col = i / 128, k = i - col * 128;
    float v = (col < 128) ? ltw[k * 128 + col] : ltw[(128 + k) * 128 + (col - 128)];
    TtxtW[i] = f32_to_bf16(v); return; } i -= 32768;
  if (i < 65536) { int col = i / 256, k = i - col * 256;
    float v = (col < 128) ? liw[k * 128 + col] : liw[(256 + k) * 128 + (col - 128)];
    TimgW[i] = f32_to_bf16(v); return; } i -= 65536;
  if (i < 768) { int t = i >> 8, j = i & 255;
    const float* b = t == 0 ? lpb : t == 1 ? ltb : lib;
    bcomb[i] = (j < 128) ? 0.f : b[j - 128]; return; } i -= 768;
  if (i < 512) {
    if (i < 256) brz[i] = gbih[i] + gbhh[i];
    else if (i < 384) binv[i - 256] = gbih[i];
    else bhnv[i - 384] = gbhh[i - 128];
  }
}

__global__ void cvtf2_k(const float* __restrict__ in, unsigned int* __restrict__ out, int n2) {
  int i = blockIdx.x * 256 + threadIdx.x;
  if (i < n2) {
    float2 v = reinterpret_cast<const float2*>(in)[i];
    out[i] = cvt_pk_bf16(v.x, v.y);
  }
}

// ---------------- CSR build ----------------
__global__ void fill_zero_k(float* __restrict__ p, int n) {
  int i = blockIdx.x * 256 + threadIdx.x;
  if (i < n) p[i] = 0.f;
}

__global__ void histo_k(const int* __restrict__ eidx, int* __restrict__ ideg) {
  int e = blockIdx.x * 256 + threadIdx.x;
  if (e < NE) atomicAdd(&ideg[eidx[NE + e]], 1);
}

__global__ void scan_k(const int* __restrict__ ideg, int* __restrict__ rowptr) {
  __shared__ int sh[256];
  __shared__ int carry;
  const int tid = threadIdx.x;
  if (tid == 0) carry = 0;
  __syncthreads();
  for (int base = 0; base < NN; base += 256) {
    int v = (base + tid < NN) ? ideg[base + tid] : 0;
    sh[tid] = v;
    __syncthreads();
#pragma unroll
    for (int off = 1; off < 256; off <<= 1) {
      int t = (tid >= off) ? sh[tid - off] : 0;
      __syncthreads();
      sh[tid] += t;
      __syncthreads();
    }
    if (base + tid < NN) rowptr[base + tid] = carry + sh[tid] - v;
    __syncthreads();
    if (tid == 255) carry += sh[255];
    __syncthreads();
  }
  if (tid == 0) rowptr[NN] = carry;
}

__global__ void dinv_csr_k(const int* __restrict__ rowptr, float* __restrict__ dinv) {
  int i = blockIdx.x * 256 + threadIdx.x;
  if (i < NN) dinv[i] = rsqrtf((float)(rowptr[i + 1] - rowptr[i]) + 1.f);
}

__global__ void scatter_k(const int* __restrict__ eidx, int* __restrict__ cursor,
                          int* __restrict__ esrc_s, int* __restrict__ edst_s,
                          int* __restrict__ eorig_s) {
  int e = blockIdx.x * 256 + threadIdx.x;
  if (e >= NE) return;
  int s = eidx[e], d = eidx[NE + e];
  int pos = atomicAdd(&cursor[d], 1);
  esrc_s[pos] = s;
  edst_s[pos] = d;
  eorig_s[pos] = e;
}

// ---------------- conv1: xws1 = (x @ w1) * dinv[row], bf16 ----------------
__global__ void xw1_k(const float* __restrict__ x, const float* __restrict__ w,
                      const float* __restrict__ dinv, unsigned int* __restrict__ xws) {
  int i = blockIdx.x * 256 + threadIdx.x; // over NN*64 (2 cols per thread)
  if (i >= NN * 64) return;
  int n = i >> 6, c2 = (i & 63) * 2;
  float a0 = 0.f, a1 = 0.f;
#pragma unroll
  for (int k = 0; k < 8; ++k) {
    float xv = x[n * 8 + k];
    a0 += xv * w[k * 128 + c2];
    a1 += xv * w[k * 128 + c2 + 1];
  }
  float dn = dinv[n];
  xws[i] = cvt_pk_bf16(a0 * dn, a1 * dn);
}

// ---------------- atomic-free GCN aggregate over prescaled bf16 rows -----------
// h[d] = relu(dd * (sum_{s in N(d)} xws[s] + xws[d]) + bias), one wave per node.
__global__ __launch_bounds__(256) void gcn_csr_k(
    const int* __restrict__ rowptr, const int* __restrict__ esrc_s,
    const unsigned int* __restrict__ xws, const float* __restrict__ dinv,
    const float* __restrict__ bias, unsigned int* __restrict__ outB)
{
  int node = blockIdx.x * 4 + (threadIdx.x >> 6);
  int lane = threadIdx.x & 63;
  if (node >= NN) return;
  float dd = dinv[node];
  int beg = rowptr[node], end = rowptr[node + 1];
  float a0 = 0.f, a1 = 0.f;
  int i = beg;
  for (; i + 1 < end; i += 2) {
    int s0 = esrc_s[i], s1 = esrc_s[i + 1];
    unsigned int u0 = xws[s0 * 64 + lane];
    unsigned int u1 = xws[s1 * 64 + lane];
    a0 += __uint_as_float(u0 << 16) + __uint_as_float(u1 << 16);
    a1 += __uint_as_float(u0 & 0xffff0000u) + __uint_as_float(u1 & 0xffff0000u);
  }
  if (i < end) {
    unsigned int u = xws[esrc_s[i] * 64 + lane];
    a0 += __uint_as_float(u << 16);
    a1 += __uint_as_float(u & 0xffff0000u);
  }
  unsigned int un = xws[node * 64 + lane];
  a0 += __uint_as_float(un << 16);
  a1 += __uint_as_float(un & 0xffff0000u);
  a0 = fmaxf(a0 * dd + bias[lane * 2], 0.f);
  a1 = fmaxf(a1 * dd + bias[lane * 2 + 1], 0.f);
  outB[node * 64 + lane] = cvt_pk_bf16(a0, a1);
}

// ---------------- direct-fragment MFMA GEMM (bf16 A, bf16 WT[col][K]) --------
template<int KDIM, int NCOLS, bool OUTBF16, bool ADDBIAS, bool SCALEROW>
__global__ __launch_bounds__(256) void gemm_mfma_k(
    const unsigned short* __restrict__ A, const unsigned short* __restrict__ WT,
    const float* __restrict__ bias, const float* __restrict__ rowscale,
    void* __restrict__ Cv, int M)
{
  const int tid = threadIdx.x;
  const int wid = tid >> 6, lane = tid & 63;
  const int l16 = lane & 15, lk = lane >> 4;
  const int bm = blockIdx.x * 128, bn = blockIdx.y * 128;
  const int wr = wid * 32;

  int row[2];
#pragma unroll
  for (int mf = 0; mf < 2; ++mf) {
    int r = bm + wr + mf * 16 + l16;
    row[mf] = r < M ? r : M - 1;
  }
  f32x4 acc[2][8];
#pragma unroll
  for (int mf = 0; mf < 2; ++mf)
#pragma unroll
    for (int nf = 0; nf < 8; ++nf) acc[mf][nf] = f32x4{0.f, 0.f, 0.f, 0.f};

#pragma unroll
  for (int kc = 0; kc < KDIM / 32; ++kc) {
    short8v a[2];
#pragma unroll
    for (int mf = 0; mf < 2; ++mf)
      a[mf] = *reinterpret_cast<const short8v*>(&A[(size_t)row[mf] * KDIM + kc * 32 + lk * 8]);
#pragma unroll
    for (int nf = 0; nf < 8; ++nf) {
      int col = bn + nf * 16 + l16;
      short8v b = *reinterpret_cast<const short8v*>(&WT[(size_t)col * KDIM + kc * 32 + lk * 8]);
      acc[0][nf] = MFMA_BF16(a[0], b, acc[0][nf]);
      acc[1][nf] = MFMA_BF16(a[1], b, acc[1][nf]);
    }
  }
#pragma unroll
  for (int mf = 0; mf < 2; ++mf)
#pragma unroll
    for (int nf = 0; nf < 8; ++nf) {
      int col = bn + nf * 16 + l16;
      float bb = ADDBIAS ? bias[col] : 0.f;
#pragma unroll
      for (int reg = 0; reg < 4; ++reg) {
        int r = bm + wr + mf * 16 + lk * 4 + reg;
        if (r < M) {
          float v = acc[mf][nf][reg] + bb;
          if (SCALEROW) v *= rowscale[r];
          if (OUTBF16) ((unsigned short*)Cv)[(size_t)r * NCOLS + col] = f32_to_bf16(v);
          else         ((float*)Cv)[(size_t)r * NCOLS + col] = v;
        }
      }
    }
}

// ---------------- fused persistent GRU (32 nodes/block, weights in registers) --
__global__ __launch_bounds__(256, 2) void gru_fused_k(
    const int* __restrict__ xtext, const float* __restrict__ embed,
    const unsigned short* __restrict__ wihB, const unsigned short* __restrict__ whhB,
    const float* __restrict__ brz, const float* __restrict__ binv, const float* __restrict__ bhnv,
    unsigned short* __restrict__ txt)
{
  __shared__ unsigned char hs[2][32 * 256]; // h bf16 [32][128], swizzled, dbuf
  __shared__ unsigned char xs[32 * 128];    // xt bf16 [32][64], swizzled
  const int tid = threadIdx.x;
  const int n0 = blockIdx.x * 32;
  const int wid = tid >> 6, lane = tid & 63;
  const int l16 = lane & 15, lk = lane >> 4;

  for (int i = tid; i < 32 * 256 / 4; i += 256) ((unsigned int*)hs[0])[i] = 0u;

  short8v wR[2][2], wZ[2][2], wN[2][2];
  short8v uR[2][4], uZ[2][4], uN[2][4];
  float bRr[2], bZr[2], bIr[2], bHr[2];
#pragma unroll
  for (int cf = 0; cf < 2; ++cf) {
    int col = wid * 32 + cf * 16 + l16;
#pragma unroll
    for (int ks = 0; ks < 2; ++ks) {
      wR[cf][ks] = *reinterpret_cast<const short8v*>(&wihB[(col      ) * 64 + ks * 32 + lk * 8]);
      wZ[cf][ks] = *reinterpret_cast<const short8v*>(&wihB[(col + 128) * 64 + ks * 32 + lk * 8]);
      wN[cf][ks] = *reinterpret_cast<const short8v*>(&wihB[(col + 256) * 64 + ks * 32 + lk * 8]);
    }
#pragma unroll
    for (int ks = 0; ks < 4; ++ks) {
      uR[cf][ks] = *reinterpret_cast<const short8v*>(&whhB[(col      ) * 128 + ks * 32 + lk * 8]);
      uZ[cf][ks] = *reinterpret_cast<const short8v*>(&whhB[(col + 128) * 128 + ks * 32 + lk * 8]);
      uN[cf][ks] = *reinterpret_cast<const short8v*>(&whhB[(col + 256) * 128 + ks * 32 + lk * 8]);
    }
    bRr[cf] = brz[col]; bZr[cf] = brz[128 + col];
    bIr[cf] = binv[col]; bHr[cf] = bhnv[col];
  }

  f32x4 txtacc[2][2];
#pragma unroll
  for (int mf = 0; mf < 2; ++mf)
#pragma unroll
    for (int cf = 0; cf < 2; ++cf) txtacc[mf][cf] = f32x4{0.f, 0.f, 0.f, 0.f};

  int cur = 0;
  for (int t = 0; t < LL; ++t) {
    __syncthreads();
    { // stage xt tile (32 rows x 64 cols bf16, swizzled)
      const int k4 = tid & 15, r0 = tid >> 4;
#pragma unroll
      for (int rep = 0; rep < 2; ++rep) {
        int row = r0 + rep * 16;
        int n = n0 + row; if (n >= NN) n = NN - 1;
        int tok = xtext[n * LL + t];
        float4 v = *reinterpret_cast<const float4*>(&embed[(size_t)tok * TT + k4 * 4]);
        ushort4 w;
        w.x = f32_to_bf16(v.x); w.y = f32_to_bf16(v.y);
        w.z = f32_to_bf16(v.z); w.w = f32_to_bf16(v.w);
        *reinterpret_cast<ushort4*>(&xs[row * 128 + ((k4 * 8) ^ ((row & 7) << 4))]) = w;
      }
    }
    __syncthreads();

#pragma unroll
    for (int mf = 0; mf < 2; ++mf) {
      const int arow = mf * 16 + l16;
      const int asw = (arow & 7) << 4;
      short8v ax[2], ah[4];
#pragma unroll
      for (int ks = 0; ks < 2; ++ks)
        ax[ks] = *reinterpret_cast<const short8v*>(&xs[arow * 128 + ((ks * 64 + lk * 16) ^ asw)]);
#pragma unroll
      for (int ks = 0; ks < 4; ++ks)
        ah[ks] = *reinterpret_cast<const short8v*>(&hs[cur][arow * 256 + ((ks * 64 + lk * 16) ^ asw)]);

      f32x4 aR[2], aZ[2], aI[2], aHn[2];
#pragma unroll
      for (int cf = 0; cf < 2; ++cf) {
        aR[cf] = f32x4{0.f, 0.f, 0.f, 0.f}; aZ[cf] = f32x4{0.f, 0.f, 0.f, 0.f};
        aI[cf] = f32x4{0.f, 0.f, 0.f, 0.f}; aHn[cf] = f32x4{0.f, 0.f, 0.f, 0.f};
#pragma unroll
        for (int ks = 0; ks < 2; ++ks) {
          aR[cf] = MFMA_BF16(ax[ks], wR[cf][ks], aR[cf]);
          aZ[cf] = MFMA_BF16(ax[ks], wZ[cf][ks], aZ[cf]);
          aI[cf] = MFMA_BF16(ax[ks], wN[cf][ks], aI[cf]);
        }
#pragma unroll
        for (int ks = 0; ks < 4; ++ks) {
          aR[cf]  = MFMA_BF16(ah[ks], uR[cf][ks], aR[cf]);
          aZ[cf]  = MFMA_BF16(ah[ks], uZ[cf][ks], aZ[cf]);
          aHn[cf] = MFMA_BF16(ah[ks], uN[cf][ks], aHn[cf]);
        }
      }

#pragma unroll
      for (int cf = 0; cf < 2; ++cf) {
        const int j = wid * 32 + cf * 16 + l16;
#pragma unroll
        for (int reg = 0; reg < 4; ++reg) {
          const int row = mf * 16 + lk * 4 + reg;
          const int byte = row * 256 + ((j * 2) ^ ((row & 7) << 4));
          float hold = bf16_to_f32(*reinterpret_cast<unsigned short*>(&hs[cur][byte]));
          float rg = fast_sigmoid(aR[cf][reg] + bRr[cf]);
          float zg = fast_sigmoid(aZ[cf][reg] + bZr[cf]);
          float ng = fast_tanh(aI[cf][reg] + bIr[cf] + rg * (aHn[cf][reg] + bHr[cf]));
          float h2 = (1.f - zg) * ng + zg * hold;
          txtacc[mf][cf][reg] += h2;
          *reinterpret_cast<unsigned short*>(&hs[cur ^ 1][byte]) = f32_to_bf16(h2);
        }
      }
    }
    cur ^= 1;
  }

#pragma unroll
  for (int mf = 0; mf < 2; ++mf)
#pragma unroll
    for (int cf = 0; cf < 2; ++cf) {
      const int j = wid * 32 + cf * 16 + l16;
#pragma unroll
      for (int reg = 0; reg < 4; ++reg) {
        const int row = mf * 16 + lk * 4 + reg;
        const int n = n0 + row;
        if (n < NN) txt[(size_t)n * HH + j] = f32_to_bf16(txtacc[mf][cf][reg]);
      }
    }
}

// ---------------- fused edge heads: sequential heads, deep-prefetch gathers ----
// 128 edges/block, 4 waves x 32 edges. All 24 src gathers issued up front
// (landing directly in af[]), dst ring-2. Head0 MFMAs interleave with loads;
// head1 (192 MFMAs) is pure register compute under setprio(1).
__global__ __launch_bounds__(256, 2) void edge_mfma_k(
    const int* __restrict__ esrc_s, const int* __restrict__ edst_s,
    const int* __restrict__ eorig_s,
    const unsigned short* __restrict__ Tall,
    const unsigned short* __restrict__ rw1T, const float* __restrict__ rb1,
    const float* __restrict__ rw2, const float* __restrict__ rb2,
    const unsigned short* __restrict__ cw1T, const float* __restrict__ cb1,
    const float* __restrict__ cw2, const float* __restrict__ cb2,
    float* __restrict__ out)
{
  const int tid = threadIdx.x;
  const int e0 = blockIdx.x * 128;
  const int wid = tid >> 6, lane = tid & 63;
  const int l16 = lane & 15, lk = lane >> 4;
  const int wr = wid * 32;
  const int lkoff = lk * 8;

  const int ea = e0 + wr + l16, eb = e0 + wr + 16 + l16;
  const size_t soff0 = (size_t)esrc_s[ea] * 256;
  const size_t soff1 = (size_t)esrc_s[eb] * 256;
  const size_t doff0 = (size_t)edst_s[ea] * 256 + 128;
  const size_t doff1 = (size_t)edst_s[eb] * 256 + 128;

  uint4 af[6][2][2];   // combined e fragments (src raw lands here first)
  uint4 dr[2][2][2];   // dst raw ring
  f32x4 acc[2][8];
#pragma unroll
  for (int mf = 0; mf < 2; ++mf)
#pragma unroll
    for (int nf = 0; nf < 8; ++nf) acc[mf][nf] = f32x4{0.f, 0.f, 0.f, 0.f};

#define TB(c) (Tall + (size_t)((c) >> 1) * ((size_t)NN * 256) + ((c) & 1) * 64 + lkoff)
#define LSRC(c) { const unsigned short* tb = TB(c); \
  af[c][0][0] = *reinterpret_cast<const uint4*>(tb + soff0); \
  af[c][0][1] = *reinterpret_cast<const uint4*>(tb + soff0 + 32); \
  af[c][1][0] = *reinterpret_cast<const uint4*>(tb + soff1); \
  af[c][1][1] = *reinterpret_cast<const uint4*>(tb + soff1 + 32); }
#define LDST(c) { const unsigned short* tb = TB(c); \
  dr[(c) & 1][0][0] = *reinterpret_cast<const uint4*>(tb + doff0); \
  dr[(c) & 1][0][1] = *reinterpret_cast<const uint4*>(tb + doff0 + 32); \
  dr[(c) & 1][1][0] = *reinterpret_cast<const uint4*>(tb + doff1); \
  dr[(c) & 1][1][1] = *reinterpret_cast<const uint4*>(tb + doff1 + 32); }
#define COMB(c) { \
  _Pragma("unroll") for (int mf = 0; mf < 2; ++mf) \
  _Pragma("unroll") for (int ks = 0; ks < 2; ++ks) { \
    uint4 s = af[c][mf][ks], d = dr[(c) & 1][mf][ks]; \
    uint4 r; r.x = combine2(s.x, d.x); r.y = combine2(s.y, d.y); \
    r.z = combine2(s.z, d.z); r.w = combine2(s.w, d.w); \
    af[c][mf][ks] = r; } }
#define PROCH(c, W) { \
  _Pragma("unroll") for (int ks = 0; ks < 2; ++ks) { \
    short8v a0 = *reinterpret_cast<short8v*>(&af[c][0][ks]); \
    short8v a1 = *reinterpret_cast<short8v*>(&af[c][1][ks]); \
    int kglob = (c) * 64 + ks * 32 + lkoff; \
    _Pragma("unroll") for (int nf = 0; nf < 8; ++nf) { \
      int col = nf * 16 + l16; \
      short8v b = *reinterpret_cast<const short8v*>(&W[(size_t)col * 384 + kglob]); \
      acc[0][nf] = MFMA_BF16(a0, b, acc[0][nf]); \
      acc[1][nf] = MFMA_BF16(a1, b, acc[1][nf]); } } }
#define EPI(B1, W2, B2, H) { \
  _Pragma("unroll") for (int mf = 0; mf < 2; ++mf) \
  _Pragma("unroll") for (int reg = 0; reg < 4; ++reg) { \
    float p0 = 0.f, p1 = 0.f; \
    _Pragma("unroll") for (int nf = 0; nf < 8; ++nf) { \
      int col = nf * 16 + l16; \
      float hv = fmaxf(acc[mf][nf][reg] + B1[col], 0.f); \
      p0 += hv * W2[col * 2]; p1 += hv * W2[col * 2 + 1]; } \
    _Pragma("unroll") for (int m = 1; m < 16; m <<= 1) { \
      p0 += __shfl_xor(p0, m); p1 += __shfl_xor(p1, m); } \
    if (l16 == 0) { \
      int orig = eorig_s[e0 + wr + mf * 16 + lk * 4 + reg]; \
      float l0 = p0 + B2[0], l1 = p1 + B2[1]; \
      float mx = fmaxf(l0, l1); \
      float lse = mx + __logf(__expf(l0 - mx) + __expf(l1 - mx)); \
      float2 o2 = make_float2(l0 - lse, l1 - lse); \
      *reinterpret_cast<float2*>(&out[(size_t)(H) * 2 * NE + (size_t)orig * 2]) = o2; } } }

  // issue ALL src gathers (24 loads) + first two dst chunks (deep MLP)
  LSRC(0) LSRC(1) LSRC(2) LSRC(3) LSRC(4) LSRC(5)
  LDST(0) LDST(1)
  COMB(0) PROCH(0, rw1T) LDST(2)
  COMB(1) PROCH(1, rw1T) LDST(3)
  COMB(2) PROCH(2, rw1T) LDST(4)
  COMB(3) PROCH(3, rw1T) LDST(5)
  COMB(4) PROCH(4, rw1T)
  COMB(5) PROCH(5, rw1T)
  EPI(rb1, rw2, rb2, 0)

#pragma unroll
  for (int mf = 0; mf < 2; ++mf)
#pragma unroll
    for (int nf = 0; nf < 8; ++nf) acc[mf][nf] = f32x4{0.f, 0.f, 0.f, 0.f};

  __builtin_amdgcn_s_setprio(1);
  PROCH(0, cw1T) PROCH(1, cw1T) PROCH(2, cw1T)
  PROCH(3, cw1T) PROCH(4, cw1T) PROCH(5, cw1T)
  __builtin_amdgcn_s_setprio(0);
  EPI(cb1, cw2, cb2, 1)

#undef TB
#undef LSRC
#undef LDST
#undef COMB
#undef PROCH
#undef EPI
}

// ---------------- launch ----------------
extern "C" void kernel_launch(void* const* d_in, const int* in_sizes, int n_in,
                              void* d_out, int out_size, void* d_ws, size_t ws_size,
                              hipStream_t stream)
{
  const float* x       = (const float*)d_in[0];
  const int*   eidx    = (const int*)  d_in[1];
  const int*   xtext   = (const int*)  d_in[2];
  const float* imgf    = (const float*)d_in[3];
  const float* conv1_w = (const float*)d_in[4];
  const float* conv1_b = (const float*)d_in[5];
  const float* conv2_w = (const float*)d_in[6];
  const float* conv2_b = (const float*)d_in[7];
  const float* embed   = (const float*)d_in[8];
  const float* gwih    = (const float*)d_in[9];
  const float* gwhh    = (const float*)d_in[10];
  const float* gbih    = (const float*)d_in[11];
  const float* gbhh    = (const float*)d_in[12];
  const float* lpw     = (const float*)d_in[13];
  const float* lpb     = (const float*)d_in[14];
  const float* ltw     = (const float*)d_in[15];
  const float* ltb     = (const float*)d_in[16];
  const float* liw     = (const float*)d_in[17];
  const float* lib     = (const float*)d_in[18];
  const float* rw1     = (const float*)d_in[19];
  const float* rb1     = (const float*)d_in[20];
  const float* rw2     = (const float*)d_in[21];
  const float* rb2     = (const float*)d_in[22];
  const float* cw1     = (const float*)d_in[23];
  const float* cb1     = (const float*)d_in[24];
  const float* cw2     = (const float*)d_in[25];
  const float* cb2     = (const float*)d_in[26];
  float* out = (float*)d_out;

  char* w8 = (char*)d_ws;
  size_t off = 0;
  auto balloc = [&](size_t bytes) { void* p = w8 + off; off = (off + bytes + 255) & ~(size_t)255; return p; };
  float*          dinv   = (float*)balloc(NN * 4);
  int*            ideg   = (int*)balloc((NN + 1) * 4);
  int*            rowptr = (int*)balloc((NN + 1) * 4);
  int*            cursor = (int*)balloc((NN + 1) * 4);
  int*            esrc_s = (int*)balloc((size_t)NE * 4);
  int*            edst_s = (int*)balloc((size_t)NE * 4);
  int*            eorig_s= (int*)balloc((size_t)NE * 4);
  unsigned int*   xwsB   = (unsigned int*)balloc((size_t)NN * 64 * 4);   // bf16x2 [N][128]
  unsigned int*   nodeB  = (unsigned int*)balloc((size_t)NN * 64 * 4);   // h1 then pos
  unsigned short* txtB   = (unsigned short*)balloc((size_t)NN * HH * 2);
  unsigned short* imgB   = (unsigned short*)balloc((size_t)NN * 256 * 2);
  unsigned short* Tall   = (unsigned short*)balloc((size_t)3 * NN * 256 * 2);
  unsigned short* wihB   = (unsigned short*)balloc(384 * 64 * 2);
  unsigned short* whhB   = (unsigned short*)balloc(384 * 128 * 2);
  unsigned short* rw1T   = (unsigned short*)balloc(384 * 128 * 2);
  unsigned short* cw1T   = (unsigned short*)balloc(384 * 128 * 2);
  unsigned short* conv2T = (unsigned short*)balloc(128 * 128 * 2);
  unsigned short* TposW  = (unsigned short*)balloc(256 * 128 * 2);
  unsigned short* TtxtW  = (unsigned short*)balloc(256 * 128 * 2);
  unsigned short* TimgW  = (unsigned short*)balloc(256 * 256 * 2);
  float*          bcomb  = (float*)balloc(768 * 4);
  float*          brz    = (float*)balloc(256 * 4);
  float*          binv   = (float*)balloc(128 * 4);
  float*          bhnv   = (float*)balloc(128 * 4);

  dim3 b256(256);
  auto cdiv = [](int a, int b) { return (a + b - 1) / b; };
  const int MB = cdiv(NN, 128); // 157

  // ---- fused weight prep + img cast ----
  prep_k<<<cdiv(320768, 256), b256, 0, stream>>>(
      gwih, gwhh, rw1, cw1, conv2_w, lpw, ltw, liw, lpb, ltb, lib, gbih, gbhh,
      wihB, whhB, rw1T, cw1T, conv2T, TposW, TtxtW, TimgW, bcomb, brz, binv, bhnv);
  cvtf2_k<<<cdiv(NN * 128, 256), b256, 0, stream>>>(imgf, (unsigned int*)imgB, NN * 128);

  // ---- dst-sorted CSR + dinv ----
  fill_zero_k<<<cdiv(NN + 1, 256), b256, 0, stream>>>((float*)ideg, NN + 1);
  histo_k<<<cdiv(NE, 256), b256, 0, stream>>>(eidx, ideg);
  scan_k<<<1, b256, 0, stream>>>(ideg, rowptr);
  dinv_csr_k<<<cdiv(NN, 256), b256, 0, stream>>>(rowptr, dinv);
  hipMemcpyAsync(cursor, rowptr, (NN + 1) * sizeof(int), hipMemcpyDeviceToDevice, stream);
  scatter_k<<<cdiv(NE, 256), b256, 0, stream>>>(eidx, cursor, esrc_s, edst_s, eorig_s);

  // ---- GCN layer 1: prescaled bf16 rows -> CSR sum ----
  xw1_k<<<cdiv(NN * 64, 256), b256, 0, stream>>>(x, conv1_w, dinv, xwsB);
  gcn_csr_k<<<cdiv(NN, 4), b256, 0, stream>>>(rowptr, esrc_s, xwsB, dinv, conv1_b, nodeB);

  // ---- GCN layer 2: MFMA (bf16 out, row-prescaled) -> CSR sum ----
  gemm_mfma_k<128, 128, true, false, true><<<dim3(MB, 1), b256, 0, stream>>>(
      (const unsigned short*)nodeB, conv2T, nullptr, dinv, xwsB, NN);
  gcn_csr_k<<<cdiv(NN, 4), b256, 0, stream>>>(rowptr, esrc_s, xwsB, dinv, conv2_b, nodeB);

  // ---- GRU -> txt bf16 ----
  gru_fused_k<<<NN / 32, b256, 0, stream>>>(xtext, embed, wihB, whhB, brz, binv, bhnv, txtB);

  // ---- node tables (bf16, combined src|dst cols) ----
  gemm_mfma_k<128, 256, true, true, false><<<dim3(MB, 2), b256, 0, stream>>>(
      (const unsigned short*)nodeB, TposW, bcomb, nullptr, Tall, NN);
  gemm_mfma_k<128, 256, true, true, false><<<dim3(MB, 2), b256, 0, stream>>>(
      txtB, TtxtW, bcomb + 256, nullptr, Tall + (size_t)NN * 256, NN);
  gemm_mfma_k<256, 256, true, true, false><<<dim3(MB, 2), b256, 0, stream>>>(
      imgB, TimgW, bcomb + 512, nullptr, Tall + (size_t)2 * NN * 256, NN);

  // ---- fused edge heads + log_softmax (dst-sorted order) ----
  edge_mfma_k<<<NE / 128, b256, 0, stream>>>(esrc_s, edst_s, eorig_s, Tall,
                                             rw1T, rb1, rw2, rb2, cw1T, cb1, cw2, cb2, out);
}